// Round 12
// baseline (2644.912 us; speedup 1.0000x reference)
//
#include <hip/hip_runtime.h>
#include <hip/hip_bf16.h>

#define T_STEPS 512
#define BATCH 64
#define TB (T_STEPS * BATCH)   // 32768

typedef short bf16x8 __attribute__((ext_vector_type(8)));
typedef float f32x4 __attribute__((ext_vector_type(4)));

union FragU { uint4 u; bf16x8 v; };

static __device__ __forceinline__ bf16x8 ld_frag(const uint4* p) {
  FragU f; f.u = *p; return f.v;
}

static __device__ __forceinline__ unsigned short f2bf(float f) {
  unsigned u = __float_as_uint(f);
  return (unsigned short)((u + 0x7FFFu + ((u >> 16) & 1u)) >> 16);
}

static __device__ __forceinline__ unsigned cvt_pk_bf16(float lo, float hi) {
  unsigned r;
  asm("v_cvt_pk_bf16_f32 %0, %1, %2" : "=v"(r) : "v"(lo), "v"(hi));
  return r;
}

static __device__ __forceinline__ int revrow(int r) {
  int t = r >> 6, b = r & 63;
  return ((T_STEPS - 1 - t) << 6) | b;
}

#define S_RZ  (-1.4426950408889634f)
#define S_C   (-2.8853900817779268f)

// ---- explicit named-AGPR weight residency: Whrz = a0..a255 ---------------------------
#define AWR(N, x) asm volatile("v_accvgpr_write_b32 a" #N ", %0" :: "v"(x) : "a" #N)
// chain c (0..7): c<4 -> r-tile 4w+c; c>=4 -> z-tile 16+4w+(c-4). AGPR base = c*32+kt*4.
#define LDW(C, KT, A0, A1, A2, A3) do { \
    const int nt_ = 4 * w + ((C) < 4 ? (C) : 12 + (C)); \
    uint4 t = whrzp[((size_t)nt_ * 8 + (KT)) * 64 + lane]; \
    AWR(A0, t.x); AWR(A1, t.y); AWR(A2, t.z); AWR(A3, t.w); } while (0)

#define MFMA_A(acc, va, B0, B3) \
  asm volatile("v_mfma_f32_16x16x32_bf16 %0, %1, a[" #B0 ":" #B3 "], %0" \
               : "+v"(acc) : "v"(va))
#define MFMA_AZ(acc, va, B0, B3, zq) \
  asm volatile("v_mfma_f32_16x16x32_bf16 %0, %1, a[" #B0 ":" #B3 "], %2" \
               : "=&v"(acc) : "v"(va), "v"(zq))
#define MFMA_V(acc, va, vb) \
  asm volatile("v_mfma_f32_16x16x32_bf16 %0, %1, %2, %0" \
               : "+v"(acc) : "v"(va), "v"(vb))
#define MFMA_VZ(acc, va, vb, zq) \
  asm volatile("v_mfma_f32_16x16x32_bf16 %0, %1, %2, %3" \
               : "=&v"(acc) : "v"(va), "v"(vb), "v"(zq))
#define ACCFENCE4(a, b, c, d) \
  asm volatile("s_nop 7\n\ts_nop 7" : "+v"(a), "+v"(b), "+v"(c), "+v"(d))

#define ACLB \
  "a0","a1","a2","a3","a4","a5","a6","a7","a8","a9","a10","a11","a12","a13","a14","a15", \
  "a16","a17","a18","a19","a20","a21","a22","a23","a24","a25","a26","a27","a28","a29","a30","a31", \
  "a32","a33","a34","a35","a36","a37","a38","a39","a40","a41","a42","a43","a44","a45","a46","a47", \
  "a48","a49","a50","a51","a52","a53","a54","a55","a56","a57","a58","a59","a60","a61","a62","a63", \
  "a64","a65","a66","a67","a68","a69","a70","a71","a72","a73","a74","a75","a76","a77","a78","a79", \
  "a80","a81","a82","a83","a84","a85","a86","a87","a88","a89","a90","a91","a92","a93","a94","a95", \
  "a96","a97","a98","a99","a100","a101","a102","a103","a104","a105","a106","a107","a108","a109","a110","a111", \
  "a112","a113","a114","a115","a116","a117","a118","a119","a120","a121","a122","a123","a124","a125","a126","a127", \
  "a128","a129","a130","a131","a132","a133","a134","a135","a136","a137","a138","a139","a140","a141","a142","a143", \
  "a144","a145","a146","a147","a148","a149","a150","a151","a152","a153","a154","a155","a156","a157","a158","a159", \
  "a160","a161","a162","a163","a164","a165","a166","a167","a168","a169","a170","a171","a172","a173","a174","a175", \
  "a176","a177","a178","a179","a180","a181","a182","a183","a184","a185","a186","a187","a188","a189","a190","a191", \
  "a192","a193","a194","a195","a196","a197","a198","a199","a200","a201","a202","a203","a204","a205","a206","a207", \
  "a208","a209","a210","a211","a212","a213","a214","a215","a216","a217","a218","a219","a220","a221","a222","a223", \
  "a224","a225","a226","a227","a228","a229","a230","a231","a232","a233","a234","a235","a236","a237","a238","a239", \
  "a240","a241","a242","a243","a244","a245","a246","a247","a248","a249","a250","a251","a252","a253","a254","a255"

// ---------------- pack weights into MFMA B-fragment layout (with gate pre-scaling) ----
__global__ void pack_w_kernel(const float* __restrict__ W, int rows, int k_base,
                              int n_tiles, int k_tiles, int mode,
                              unsigned short* __restrict__ dst) {
  int gid = blockIdx.x * blockDim.x + threadIdx.x;
  int total = n_tiles * k_tiles * 64;
  if (gid >= total) return;
  int lane = gid & 63;
  int fi = gid >> 6;
  int kt = fi % k_tiles;
  int nt = fi / k_tiles;
  int n = nt * 16 + (lane & 15);
  int g, col; float s;
  if (mode == 0)      { g = n >> 8;            col = n & 255; s = (g == 1) ? S_C : S_RZ; }
  else if (mode == 1) { g = (n < 256) ? 0 : 2; col = n & 255; s = S_RZ; }
  else                { g = 1;                 col = n;       s = S_C; }
  int k0 = k_base + kt * 32 + ((lane >> 4) << 3);
  const float* src = W + ((size_t)g * rows + k0) * 256 + col;
  unsigned short v[8];
#pragma unroll
  for (int j = 0; j < 8; ++j) v[j] = f2bf(src[(size_t)j * 256] * s);
  uint4 o;
  o.x = v[0] | ((unsigned)v[1] << 16);
  o.y = v[2] | ((unsigned)v[3] << 16);
  o.z = v[4] | ((unsigned)v[5] << 16);
  o.w = v[6] | ((unsigned)v[7] << 16);
  ((uint4*)dst)[gid] = o;
}

static __device__ __forceinline__ bf16x8 cvt8(float4 f0, float4 f1) {
  uint4 o;
  o.x = f2bf(f0.x) | ((unsigned)f2bf(f0.y) << 16);
  o.y = f2bf(f0.z) | ((unsigned)f2bf(f0.w) << 16);
  o.z = f2bf(f1.x) | ((unsigned)f2bf(f1.y) << 16);
  o.w = f2bf(f1.z) | ((unsigned)f2bf(f1.w) << 16);
  FragU f; f.u = o; return f.v;
}

// ---------------- Xg GEMM (chunked): writes C-fragment tile layout --------------------
template<int LAYER>
__global__ __launch_bounds__(256)
void gemm_xg_kernel(const float* __restrict__ x,
                    const unsigned short* __restrict__ fs0,
                    const unsigned short* __restrict__ bs0,
                    const unsigned short* __restrict__ Bp,
                    const float* __restrict__ bias_fw,
                    const float* __restrict__ bias_bw,
                    f32x4* __restrict__ Xg, int t0, int chunkT)
{
  constexpr int KT = (LAYER == 0) ? 8 : 16;
  int dir = blockIdx.z;
  int lane = threadIdx.x & 63;
  int w = threadIdx.x >> 6;
  int ww = w >> 1, wc = w & 1;
  int mt0 = blockIdx.x * 8 + ww * 4;
  int nt0 = blockIdx.y * 8 + wc * 4;
  const uint4* B = (const uint4*)Bp + (size_t)dir * 48 * KT * 64;
  const int arow = lane & 15;
  const int k0b = ((lane >> 4) << 3);

  f32x4 acc[4][4] = {};
#pragma unroll
  for (int kt = 0; kt < KT; ++kt) {
    int k0 = kt * 32 + k0b;
    bf16x8 a[4], b[4];
#pragma unroll
    for (int i = 0; i < 4; ++i) {
      int grow = t0 * 64 + (mt0 + i) * 16 + arow;
      if (LAYER == 0) {
        int gr = dir ? revrow(grow) : grow;
        const float4* s = (const float4*)(x + (size_t)gr * 256 + k0);
        a[i] = cvt8(s[0], s[1]);
      } else {
        const unsigned short* base; int r2 = grow, kk = k0;
        if (k0 < 256) { base = dir ? bs0 : fs0; }
        else          { base = dir ? fs0 : bs0; r2 = revrow(grow); kk = k0 - 256; }
        a[i] = *(const bf16x8*)(base + (size_t)r2 * 256 + kk);
      }
    }
#pragma unroll
    for (int j = 0; j < 4; ++j) b[j] = ld_frag(B + ((size_t)(nt0 + j) * KT + kt) * 64 + lane);
#pragma unroll
    for (int i = 0; i < 4; ++i)
#pragma unroll
      for (int j = 0; j < 4; ++j)
        acc[i][j] = __builtin_amdgcn_mfma_f32_16x16x32_bf16(a[i], b[j], acc[i][j], 0, 0, 0);
  }

  const float* bias = dir ? bias_bw : bias_fw;
  f32x4* C = Xg + (size_t)dir * (chunkT * 4) * 48 * 64;
#pragma unroll
  for (int j = 0; j < 4; ++j) {
    int ct = nt0 + j;
    int col = ct * 16 + (lane & 15);
    int g = col >> 8, cc = col & 255;
    float bv = ((g == 1) ? S_C : S_RZ) * bias[g * 256 + cc];
#pragma unroll
    for (int i = 0; i < 4; ++i) {
      int rt = blockIdx.x * 8 + ww * 4 + i;
      f32x4 v = acc[i][j];
      v[0] += bv; v[1] += bv; v[2] += bv; v[3] += bv;
      C[((size_t)rt * 48 + ct) * 64 + lane] = v;
    }
  }
}

// ---------------- persistent recurrent GRU kernel: 4 waves, 1 wave/SIMD ---------------
// grid (4,2), 256 threads. Whrz: a0..a255 (8 chains x 8 kt). Whc: 2 tiles arch VGPR +
// 2 tiles LDS per wave. Full 512-reg/wave file via waves_per_eu(1,1).
template<int LAYER>
__global__ __launch_bounds__(256) __attribute__((amdgpu_waves_per_eu(1, 1)))
void gru_kernel(const f32x4* __restrict__ Xg,
                const uint4* __restrict__ whrz_fw, const uint4* __restrict__ whrz_bw, // [32][8][64]
                const uint4* __restrict__ whc_fw,  const uint4* __restrict__ whc_bw,  // [16][8][64]
                unsigned short* __restrict__ sfw_bf, unsigned short* __restrict__ sbw_bf,
                float* __restrict__ out,
                float* __restrict__ hstate, float* __restrict__ dout_h,
                int t0, int chunkT)
{
  const int dir = blockIdx.y;
  const int bx = blockIdx.x;
  const int row0 = bx * 16;
  const int tid = threadIdx.x;
  const int lane = tid & 63;
  const int w = tid >> 6;               // 0..3

  // hx: [rh bf16 swizzled 8KB][h bf16 swizzled 8KB]
  __shared__ __align__(16) unsigned short hx[2 * 16 * 256];
  __shared__ __align__(16) uint4 wc_lds[8 * 8 * 64];        // Whc LDS half (64 KB)

  const uint4* whrzp = dir ? whrz_bw : whrz_fw;
  const uint4* whcp  = dir ? whc_bw  : whc_fw;

  // stage LDS half of Whc: local tile l = 2*w_ + j -> global tile 4*w_ + 2 + j
  for (int i = tid; i < 8 * 8 * 64; i += 256) {
    int l = i >> 9, rem = i & 511;
    int nt = 4 * (l >> 1) + 2 + (l & 1);
    wc_lds[i] = whcp[(size_t)nt * 512 + rem];
  }

  // arch half of Whc: tiles 4w+0, 4w+1
  bf16x8 whcf0[8], whcf1[8];
#pragma unroll
  for (int kt = 0; kt < 8; ++kt) {
    whcf0[kt] = ld_frag(whcp + ((size_t)(4 * w + 0) * 8 + kt) * 64 + lane);
    whcf1[kt] = ld_frag(whcp + ((size_t)(4 * w + 1) * 8 + kt) * 64 + lane);
  }

  // pin Whrz into a0..a255: base(c,kt) = c*32 + kt*4
  LDW(0,0, 0,1,2,3);     LDW(0,1, 4,5,6,7);     LDW(0,2, 8,9,10,11);    LDW(0,3, 12,13,14,15);
  LDW(0,4, 16,17,18,19); LDW(0,5, 20,21,22,23); LDW(0,6, 24,25,26,27);  LDW(0,7, 28,29,30,31);
  LDW(1,0, 32,33,34,35); LDW(1,1, 36,37,38,39); LDW(1,2, 40,41,42,43);  LDW(1,3, 44,45,46,47);
  LDW(1,4, 48,49,50,51); LDW(1,5, 52,53,54,55); LDW(1,6, 56,57,58,59);  LDW(1,7, 60,61,62,63);
  LDW(2,0, 64,65,66,67); LDW(2,1, 68,69,70,71); LDW(2,2, 72,73,74,75);  LDW(2,3, 76,77,78,79);
  LDW(2,4, 80,81,82,83); LDW(2,5, 84,85,86,87); LDW(2,6, 88,89,90,91);  LDW(2,7, 92,93,94,95);
  LDW(3,0, 96,97,98,99); LDW(3,1, 100,101,102,103); LDW(3,2, 104,105,106,107); LDW(3,3, 108,109,110,111);
  LDW(3,4, 112,113,114,115); LDW(3,5, 116,117,118,119); LDW(3,6, 120,121,122,123); LDW(3,7, 124,125,126,127);
  LDW(4,0, 128,129,130,131); LDW(4,1, 132,133,134,135); LDW(4,2, 136,137,138,139); LDW(4,3, 140,141,142,143);
  LDW(4,4, 144,145,146,147); LDW(4,5, 148,149,150,151); LDW(4,6, 152,153,154,155); LDW(4,7, 156,157,158,159);
  LDW(5,0, 160,161,162,163); LDW(5,1, 164,165,166,167); LDW(5,2, 168,169,170,171); LDW(5,3, 172,173,174,175);
  LDW(5,4, 176,177,178,179); LDW(5,5, 180,181,182,183); LDW(5,6, 184,185,186,187); LDW(5,7, 188,189,190,191);
  LDW(6,0, 192,193,194,195); LDW(6,1, 196,197,198,199); LDW(6,2, 200,201,202,203); LDW(6,3, 204,205,206,207);
  LDW(6,4, 208,209,210,211); LDW(6,5, 212,213,214,215); LDW(6,6, 216,217,218,219); LDW(6,7, 220,221,222,223);
  LDW(7,0, 224,225,226,227); LDW(7,1, 228,229,230,231); LDW(7,2, 232,233,234,235); LDW(7,3, 236,237,238,239);
  LDW(7,4, 240,241,242,243); LDW(7,5, 244,245,246,247); LDW(7,6, 248,249,250,251); LDW(7,7, 252,253,254,255);

  const int ccol = lane & 15;
  const int crow = ((lane >> 4) << 2);     // 0,4,8,12

#define SWZ(rr, cb) ((rr) * 512 + ((((cb) & ~15) ^ (((rr) & 7) << 4)) | ((cb) & 15)))

  float* hst = hstate + (size_t)(dir * 4 + bx) * 4096;
  for (int i = tid; i < 16 * 256; i += 256) {
    float v = (t0 == 0) ? 0.0f : hst[i];
    int rr = i >> 8, cc = i & 255;
    *(unsigned short*)((char*)hx + 8192 + SWZ(rr, cc * 2)) = f2bf(v);
  }
  // thread-resident fp32 h: cand cols 64w + 16c + ccol, rows crow..crow+3
  float hreg[4][4];
#pragma unroll
  for (int c = 0; c < 4; ++c)
#pragma unroll
    for (int r = 0; r < 4; ++r)
      hreg[c][r] = (t0 == 0) ? 0.0f
                 : hst[(size_t)(crow + r) * 256 + 64 * w + 16 * c + ccol];
  __syncthreads();

  const f32x4* XgD = Xg + (size_t)dir * (chunkT * 4) * 48 * 64;
  unsigned short* sp_bf = dir ? sbw_bf : sfw_bf;
  const int coff = dir ? 256 : 0;
  const int ardbase = (lane & 15) * 512;
  const int arxor = ((lane & 7) << 4);
  const int afc = ((lane >> 4) << 4);

  int ra[8];
#pragma unroll
  for (int kt = 0; kt < 8; ++kt) ra[kt] = ardbase + ((kt * 64 + afc) ^ arxor);
#define HF(RA)  (*(const bf16x8*)((const char*)hx + 8192 + (RA)))
#define RHF(RA) (*(const bf16x8*)((const char*)hx + (RA)))

  // hoisted swizzled write addresses wa[c][r] (rh at wa, h at wa+8192)
  int wa[4][4];
#pragma unroll
  for (int c = 0; c < 4; ++c) {
    int cb = ((4 * w + c) * 16 + ccol) * 2;
#pragma unroll
    for (int r = 0; r < 4; ++r) wa[c][r] = SWZ(crow + r, cb);
  }

  const int wcb = w * 16384 + lane * 16;  // byte base of wave's LDS Whc tiles

  // strided Xg pointers (r at ct 4w+c, cand +16 tiles, z +32 tiles)
  const size_t XSTEP = (size_t)4 * 48 * 64;
  const f32x4* pR = XgD + (size_t)bx * 48 * 64 + (size_t)(4 * w) * 64 + lane;
  const f32x4* pC = pR + (size_t)16 * 64;
  const f32x4* pZ = pR + (size_t)32 * 64;

  // strided output pointers
  unsigned short* pSp = sp_bf + ((size_t)(t0 * 64 + row0 + crow) * 256) + 64 * w + ccol;
  const int g0 = (LAYER == 1 && dir) ? ((T_STEPS - 1 - t0) * 64 + row0) : (t0 * 64 + row0);
  float* pO = out ? out + ((size_t)(g0 + crow) * 512) + coff + 64 * w + ccol : nullptr;
  float* pO2 = pO ? pO + 2 * 512 : nullptr;
  const long long OSTEP = (LAYER == 1 && dir) ? -(long long)64 * 512 : (long long)64 * 512;

  f32x4 zq = {0.0f, 0.0f, 0.0f, 0.0f};

  // prologue: step-0 Xg (12 x f32x4)
  f32x4 xgr[4], xgz[4], xgc[4];
#pragma unroll
  for (int c = 0; c < 4; ++c) { xgr[c] = pR[c * 64]; xgz[c] = pZ[c * 64]; xgc[c] = pC[c * 64]; }

#define PAKT0(B0,B1,B2,B3,B4,B5,B6,B7,B8,B9,B10,B11,B12,B13,B14,B15) \
  { bf16x8 af = HF(ra[0]); \
    MFMA_AZ(accR0, af, B0, B1, zq);  MFMA_AZ(accR1, af, B2, B3, zq); \
    MFMA_AZ(accR2, af, B4, B5, zq);  MFMA_AZ(accR3, af, B6, B7, zq); \
    MFMA_AZ(accZ0, af, B8, B9, zq);  MFMA_AZ(accZ1, af, B10, B11, zq); \
    MFMA_AZ(accZ2, af, B12, B13, zq); MFMA_AZ(accZ3, af, B14, B15, zq); }
#define PAKT(KT,B0,B1,B2,B3,B4,B5,B6,B7,B8,B9,B10,B11,B12,B13,B14,B15) \
  { bf16x8 af = HF(ra[KT]); \
    MFMA_A(accR0, af, B0, B1);  MFMA_A(accR1, af, B2, B3); \
    MFMA_A(accR2, af, B4, B5);  MFMA_A(accR3, af, B6, B7); \
    MFMA_A(accZ0, af, B8, B9);  MFMA_A(accZ1, af, B10, B11); \
    MFMA_A(accZ2, af, B12, B13); MFMA_A(accZ3, af, B14, B15); }

#pragma unroll 1
  for (int t = t0; t < t0 + chunkT; ++t) {
    // ---------- phase A: rz = h @ Whrz (8 chains, all weights in AGPR) ----------
    f32x4 accR0, accR1, accR2, accR3, accZ0, accZ1, accZ2, accZ3;
    PAKT0(   0,3,   32,35,  64,67,  96,99,   128,131, 160,163, 192,195, 224,227);
    PAKT(1,  4,7,   36,39,  68,71,  100,103, 132,135, 164,167, 196,199, 228,231);
    PAKT(2,  8,11,  40,43,  72,75,  104,107, 136,139, 168,171, 200,203, 232,235);
    PAKT(3, 12,15,  44,47,  76,79,  108,111, 140,143, 172,175, 204,207, 236,239);
    PAKT(4, 16,19,  48,51,  80,83,  112,115, 144,147, 176,179, 208,211, 240,243);
    PAKT(5, 20,23,  52,55,  84,87,  116,119, 148,151, 180,183, 212,215, 244,247);
    PAKT(6, 24,27,  56,59,  88,91,  120,123, 152,155, 184,187, 216,219, 248,251);
    PAKT(7, 28,31,  60,63,  92,95,  124,127, 156,159, 188,191, 220,223, 252,255);
    ACCFENCE4(accR0, accR1, accR2, accR3);

    // epilogue A: r-gates -> rh LDS (packed bf16)
#pragma unroll
    for (int c = 0; c < 4; ++c) {
      f32x4 ac = (c == 0) ? accR0 : (c == 1) ? accR1 : (c == 2) ? accR2 : accR3;
      float rh[4];
#pragma unroll
      for (int r = 0; r < 4; ++r) {
        float v = ac[r] + xgr[c][r];
        rh[r] = __builtin_amdgcn_rcpf(1.0f + __builtin_amdgcn_exp2f(v)) * hreg[c][r];
      }
      unsigned p01 = cvt_pk_bf16(rh[0], rh[1]);
      unsigned p23 = cvt_pk_bf16(rh[2], rh[3]);
      *(unsigned short*)((char*)hx + wa[c][0]) = (unsigned short)p01;
      *(unsigned short*)((char*)hx + wa[c][1]) = (unsigned short)(p01 >> 16);
      *(unsigned short*)((char*)hx + wa[c][2]) = (unsigned short)p23;
      *(unsigned short*)((char*)hx + wa[c][3]) = (unsigned short)(p23 >> 16);
    }
    asm volatile("s_waitcnt lgkmcnt(0)" ::: "memory", ACLB);
    __builtin_amdgcn_s_barrier();

    // ---------- phase B: cand = (r*h) @ Whc (2 arch tiles + 2 LDS tiles) ----------
    f32x4 accB0, accB1, accB2, accB3;
    {
      bf16x8 a, b2, b3;
      a = RHF(ra[0]);
      b2 = *(const bf16x8*)((const char*)wc_lds + wcb + 0 * 1024);
      b3 = *(const bf16x8*)((const char*)wc_lds + wcb + 8192 + 0 * 1024);
      MFMA_VZ(accB0, a, whcf0[0], zq); MFMA_VZ(accB1, a, whcf1[0], zq);
      MFMA_VZ(accB2, a, b2, zq);       MFMA_VZ(accB3, a, b3, zq);
#pragma unroll
      for (int kt = 1; kt < 8; ++kt) {
        a = RHF(ra[kt]);
        b2 = *(const bf16x8*)((const char*)wc_lds + wcb + kt * 1024);
        b3 = *(const bf16x8*)((const char*)wc_lds + wcb + 8192 + kt * 1024);
        MFMA_V(accB0, a, whcf0[kt]); MFMA_V(accB1, a, whcf1[kt]);
        MFMA_V(accB2, a, b2);        MFMA_V(accB3, a, b3);
      }
    }

    // deferred z epilogue (overlaps phase-B MFMA pipe)
    ACCFENCE4(accZ0, accZ1, accZ2, accZ3);
    float zreg[4][4];
#pragma unroll
    for (int c = 0; c < 4; ++c) {
      f32x4 ac = (c == 0) ? accZ0 : (c == 1) ? accZ1 : (c == 2) ? accZ2 : accZ3;
#pragma unroll
      for (int r = 0; r < 4; ++r)
        zreg[c][r] = __builtin_amdgcn_rcpf(1.0f + __builtin_amdgcn_exp2f(ac[r] + xgz[c][r]));
    }

    ACCFENCE4(accB0, accB1, accB2, accB3);
    // epilogue B: cand, h update, LDS h write, global store
#pragma unroll
    for (int c = 0; c < 4; ++c) {
      f32x4 ac = (c == 0) ? accB0 : (c == 1) ? accB1 : (c == 2) ? accB2 : accB3;
      float hn[4];
#pragma unroll
      for (int r = 0; r < 4; ++r) {
        float v = ac[r] + xgc[c][r];
        float cand = __builtin_amdgcn_rcpf(1.0f + __builtin_amdgcn_exp2f(v)) * 2.0f - 1.0f;
        hn[r] = cand + zreg[c][r] * (hreg[c][r] - cand);
        hreg[c][r] = hn[r];
      }
      unsigned p01 = cvt_pk_bf16(hn[0], hn[1]);
      unsigned p23 = cvt_pk_bf16(hn[2], hn[3]);
      *(unsigned short*)((char*)hx + 8192 + wa[c][0]) = (unsigned short)p01;
      *(unsigned short*)((char*)hx + 8192 + wa[c][1]) = (unsigned short)(p01 >> 16);
      *(unsigned short*)((char*)hx + 8192 + wa[c][2]) = (unsigned short)p23;
      *(unsigned short*)((char*)hx + 8192 + wa[c][3]) = (unsigned short)(p23 >> 16);
      if (LAYER == 0) {
        pSp[c * 16 + 0 * 256] = (unsigned short)p01;
        pSp[c * 16 + 1 * 256] = (unsigned short)(p01 >> 16);
        pSp[c * 16 + 2 * 256] = (unsigned short)p23;
        pSp[c * 16 + 3 * 256] = (unsigned short)(p23 >> 16);
      } else {
        pO[c * 16 + 0 * 512] = hn[0];
        pO[c * 16 + 1 * 512] = hn[1];
        pO2[c * 16 + 0 * 512] = hn[2];
        pO2[c * 16 + 1 * 512] = hn[3];
      }
    }
    if (LAYER == 0) pSp += (size_t)64 * 256;
    else { pO += OSTEP; pO2 += OSTEP; }

    // prefetch next step's Xg (in flight across barrier; buffer is padded)
    pR += XSTEP; pZ += XSTEP; pC += XSTEP;
#pragma unroll
    for (int c = 0; c < 4; ++c) { xgr[c] = pR[c * 64]; xgz[c] = pZ[c * 64]; xgc[c] = pC[c * 64]; }

    asm volatile("s_waitcnt lgkmcnt(0)" ::: "memory", ACLB);
    __builtin_amdgcn_s_barrier();
  }

  // persist h; on last chunk also write fh/bh
#pragma unroll
  for (int c = 0; c < 4; ++c)
#pragma unroll
    for (int r = 0; r < 4; ++r) {
      int rr = crow + r, col = 64 * w + 16 * c + ccol;
      hst[(size_t)rr * 256 + col] = hreg[c][r];
      if (t0 + chunkT == T_STEPS) {
        float* dst = dout_h + (dir ? 32768 : 0) + (size_t)LAYER * 16384;
        dst[(size_t)(row0 + rr) * 256 + col] = hreg[c][r];
      }
    }
}

__global__ void diag_kernel(float* out, float v) { out[0] = v; }

// --------------------------------------------------------------------------------------
extern "C" void kernel_launch(void* const* d_in, const int* in_sizes, int n_in,
                              void* d_out, int out_size, void* d_ws, size_t ws_size,
                              hipStream_t stream) {
  const float* x     = (const float*)d_in[0];
  const float* fw_W0 = (const float*)d_in[2];
  const float* fw_b0 = (const float*)d_in[3];
  const float* fw_W1 = (const float*)d_in[4];
  const float* fw_b1 = (const float*)d_in[5];
  const float* bw_W0 = (const float*)d_in[6];
  const float* bw_b0 = (const float*)d_in[7];
  const float* bw_W1 = (const float*)d_in[8];
  const float* bw_b1 = (const float*)d_in[9];

  char* ws = (char*)d_ws;
  size_t off = 0;
  auto alloc = [&](size_t bytes) -> char* {
    char* p = ws + off; off += (bytes + 255) & ~(size_t)255; return p;
  };
  unsigned short* Wx0p  = (unsigned short*)alloc(2ull * 48 * 8 * 64 * 8 * 2);
  unsigned short* Wx1p  = (unsigned short*)alloc(2ull * 48 * 16 * 64 * 8 * 2);
  unsigned short* Whrz0 = (unsigned short*)alloc(2ull * 32 * 8 * 64 * 8 * 2);
  unsigned short* Whc0  = (unsigned short*)alloc(2ull * 16 * 8 * 64 * 8 * 2);
  unsigned short* Whrz1 = (unsigned short*)alloc(2ull * 32 * 8 * 64 * 8 * 2);
  unsigned short* Whc1  = (unsigned short*)alloc(2ull * 16 * 8 * 64 * 8 * 2);
  unsigned short* fs0   = (unsigned short*)alloc((size_t)TB * 256 * 2);
  unsigned short* bs0   = (unsigned short*)alloc((size_t)TB * 256 * 2);
  float* hstate         = (float*)alloc(2ull * 4 * 16 * 256 * 4);

  const size_t XPAD = (size_t)4 * 48 * 64 * 16;
  int chunkT = 0;
  for (int ct = 512; ct >= 8; ct >>= 1) {
    if (off + (size_t)ct * 2 * 64 * 768 * 4 + XPAD <= ws_size) { chunkT = ct; break; }
  }
  float* out = (float*)d_out;
  if (chunkT == 0) {
    diag_kernel<<<1, 1, 0, stream>>>(out, 12345.0f);
    return;
  }
  f32x4* Xg = (f32x4*)alloc((size_t)chunkT * 2 * 64 * 768 * 4 + XPAD);
  float* dout_h = out + (size_t)TB * 512;

  auto packw = [&](const float* W, int rows, int kb, int ntl, int ktl, int mode, unsigned short* dst) {
    int total = ntl * ktl * 64;
    pack_w_kernel<<<(total + 255) / 256, 256, 0, stream>>>(W, rows, kb, ntl, ktl, mode, dst);
  };
  packw(fw_W0, 512, 0,   48, 8,  0, Wx0p);
  packw(bw_W0, 512, 0,   48, 8,  0, Wx0p + 48 * 8 * 64 * 8);
  packw(fw_W1, 768, 0,   48, 16, 0, Wx1p);
  packw(bw_W1, 768, 0,   48, 16, 0, Wx1p + 48 * 16 * 64 * 8);
  packw(fw_W0, 512, 256, 32, 8,  1, Whrz0);
  packw(bw_W0, 512, 256, 32, 8,  1, Whrz0 + 32 * 8 * 64 * 8);
  packw(fw_W0, 512, 256, 16, 8,  2, Whc0);
  packw(bw_W0, 512, 256, 16, 8,  2, Whc0 + 16 * 8 * 64 * 8);
  packw(fw_W1, 768, 512, 32, 8,  1, Whrz1);
  packw(bw_W1, 768, 512, 32, 8,  1, Whrz1 + 32 * 8 * 64 * 8);
  packw(fw_W1, 768, 512, 16, 8,  2, Whc1);
  packw(bw_W1, 768, 512, 16, 8,  2, Whc1 + 16 * 8 * 64 * 8);

  dim3 rgrid(4, 2);
  // layer 0
  for (int t0 = 0; t0 < T_STEPS; t0 += chunkT) {
    dim3 ggrid(chunkT / 2, 6, 2);
    gemm_xg_kernel<0><<<ggrid, 256, 0, stream>>>(x, nullptr, nullptr, Wx0p, fw_b0, bw_b0, Xg, t0, chunkT);
    gru_kernel<0><<<rgrid, 256, 0, stream>>>(Xg,
        (const uint4*)Whrz0, (const uint4*)(Whrz0 + 32 * 8 * 64 * 8),
        (const uint4*)Whc0,  (const uint4*)(Whc0 + 16 * 8 * 64 * 8),
        fs0, bs0, nullptr, hstate, dout_h, t0, chunkT);
  }
  // layer 1
  for (int t0 = 0; t0 < T_STEPS; t0 += chunkT) {
    dim3 ggrid(chunkT / 2, 6, 2);
    gemm_xg_kernel<1><<<ggrid, 256, 0, stream>>>(nullptr, fs0, bs0, Wx1p, fw_b1, bw_b1, Xg, t0, chunkT);
    gru_kernel<1><<<rgrid, 256, 0, stream>>>(Xg,
        (const uint4*)Whrz1, (const uint4*)(Whrz1 + 32 * 8 * 64 * 8),
        (const uint4*)Whc1,  (const uint4*)(Whc1 + 16 * 8 * 64 * 8),
        nullptr, nullptr, out, hstate, dout_h, t0, chunkT);
  }
}

// Round 13
// 2480.379 us; speedup vs baseline: 1.0663x; 1.0663x over previous
//
#include <hip/hip_runtime.h>
#include <hip/hip_bf16.h>

#define T_STEPS 512
#define BATCH 64
#define TB (T_STEPS * BATCH)   // 32768

typedef short bf16x8 __attribute__((ext_vector_type(8)));
typedef float f32x4 __attribute__((ext_vector_type(4)));

union FragU { uint4 u; bf16x8 v; };

static __device__ __forceinline__ bf16x8 ld_frag(const uint4* p) {
  FragU f; f.u = *p; return f.v;
}

static __device__ __forceinline__ unsigned short f2bf(float f) {
  unsigned u = __float_as_uint(f);
  return (unsigned short)((u + 0x7FFFu + ((u >> 16) & 1u)) >> 16);
}

// packed f32->bf16 (RNE), 1 inst per pair
static __device__ __forceinline__ unsigned cvt_pk_bf16(float lo, float hi) {
  unsigned r;
  asm("v_cvt_pk_bf16_f32 %0, %1, %2" : "=v"(r) : "v"(lo), "v"(hi));
  return r;
}

static __device__ __forceinline__ int revrow(int r) {
  int t = r >> 6, b = r & 63;
  return ((T_STEPS - 1 - t) << 6) | b;
}

#define S_RZ  (-1.4426950408889634f)
#define S_C   (-2.8853900817779268f)

// ---- explicit named-AGPR weight residency (round-8..11-validated) --------------------
#define AWR(N, x) asm volatile("v_accvgpr_write_b32 a" #N ", %0" :: "v"(x) : "a" #N)
#define LOADF(F, A0, A1, A2, A3) do { \
    const int c_ = (F) >> 3, kt_ = (F) & 7; \
    const int nt_ = (c_ < 2) ? (w * 2 + c_) : (14 + w * 2 + c_); \
    uint4 t = whrzp[((size_t)nt_ * 8 + kt_) * 64 + lane]; \
    AWR(A0, t.x); AWR(A1, t.y); AWR(A2, t.z); AWR(A3, t.w); } while (0)

#define MFMA_A(acc, va, B0, B3) \
  asm volatile("v_mfma_f32_16x16x32_bf16 %0, %1, a[" #B0 ":" #B3 "], %0" \
               : "+v"(acc) : "v"(va))
#define MFMA_AZ(acc, va, B0, B3, zq) \
  asm volatile("v_mfma_f32_16x16x32_bf16 %0, %1, a[" #B0 ":" #B3 "], %2" \
               : "=&v"(acc) : "v"(va), "v"(zq))
#define MFMA_V(acc, va, vb) \
  asm volatile("v_mfma_f32_16x16x32_bf16 %0, %1, %2, %0" \
               : "+v"(acc) : "v"(va), "v"(vb))
#define MFMA_VZ(acc, va, vb, zq) \
  asm volatile("v_mfma_f32_16x16x32_bf16 %0, %1, %2, %3" \
               : "=&v"(acc) : "v"(va), "v"(vb), "v"(zq))
#define ACCFENCE2(a, b) asm volatile("s_nop 7\n\ts_nop 7" : "+v"(a), "+v"(b))
#define ACCFENCE4(a, b, c, d) \
  asm volatile("s_nop 7\n\ts_nop 7" : "+v"(a), "+v"(b), "+v"(c), "+v"(d))

#define ACLB \
  "a0","a1","a2","a3","a4","a5","a6","a7","a8","a9","a10","a11","a12","a13","a14","a15", \
  "a16","a17","a18","a19","a20","a21","a22","a23","a24","a25","a26","a27","a28","a29","a30","a31", \
  "a32","a33","a34","a35","a36","a37","a38","a39","a40","a41","a42","a43","a44","a45","a46","a47", \
  "a48","a49","a50","a51","a52","a53","a54","a55","a56","a57","a58","a59","a60","a61","a62","a63", \
  "a64","a65","a66","a67","a68","a69","a70","a71","a72","a73","a74","a75","a76","a77","a78","a79", \
  "a80","a81","a82","a83","a84","a85","a86","a87","a88","a89","a90","a91","a92","a93","a94","a95", \
  "a96","a97","a98","a99","a100","a101","a102","a103","a104","a105","a106","a107","a108","a109","a110","a111", \
  "a112","a113","a114","a115","a116","a117","a118","a119","a120","a121","a122","a123","a124","a125","a126","a127"

// ---------------- pack weights into MFMA B-fragment layout (with gate pre-scaling) ----
__global__ void pack_w_kernel(const float* __restrict__ W, int rows, int k_base,
                              int n_tiles, int k_tiles, int mode,
                              unsigned short* __restrict__ dst) {
  int gid = blockIdx.x * blockDim.x + threadIdx.x;
  int total = n_tiles * k_tiles * 64;
  if (gid >= total) return;
  int lane = gid & 63;
  int fi = gid >> 6;
  int kt = fi % k_tiles;
  int nt = fi / k_tiles;
  int n = nt * 16 + (lane & 15);
  int g, col; float s;
  if (mode == 0)      { g = n >> 8;            col = n & 255; s = (g == 1) ? S_C : S_RZ; }
  else if (mode == 1) { g = (n < 256) ? 0 : 2; col = n & 255; s = S_RZ; }
  else                { g = 1;                 col = n;       s = S_C; }
  int k0 = k_base + kt * 32 + ((lane >> 4) << 3);
  const float* src = W + ((size_t)g * rows + k0) * 256 + col;
  unsigned short v[8];
#pragma unroll
  for (int j = 0; j < 8; ++j) v[j] = f2bf(src[(size_t)j * 256] * s);
  uint4 o;
  o.x = v[0] | ((unsigned)v[1] << 16);
  o.y = v[2] | ((unsigned)v[3] << 16);
  o.z = v[4] | ((unsigned)v[5] << 16);
  o.w = v[6] | ((unsigned)v[7] << 16);
  ((uint4*)dst)[gid] = o;
}

static __device__ __forceinline__ bf16x8 cvt8(float4 f0, float4 f1) {
  uint4 o;
  o.x = f2bf(f0.x) | ((unsigned)f2bf(f0.y) << 16);
  o.y = f2bf(f0.z) | ((unsigned)f2bf(f0.w) << 16);
  o.z = f2bf(f1.x) | ((unsigned)f2bf(f1.y) << 16);
  o.w = f2bf(f1.z) | ((unsigned)f2bf(f1.w) << 16);
  FragU f; f.u = o; return f.v;
}

// ---------------- Xg GEMM (chunked): writes C-fragment tile layout --------------------
template<int LAYER>
__global__ __launch_bounds__(256)
void gemm_xg_kernel(const float* __restrict__ x,
                    const unsigned short* __restrict__ fs0,
                    const unsigned short* __restrict__ bs0,
                    const unsigned short* __restrict__ Bp,
                    const float* __restrict__ bias_fw,
                    const float* __restrict__ bias_bw,
                    f32x4* __restrict__ Xg, int t0, int chunkT)
{
  constexpr int KT = (LAYER == 0) ? 8 : 16;
  int dir = blockIdx.z;
  int lane = threadIdx.x & 63;
  int w = threadIdx.x >> 6;
  int ww = w >> 1, wc = w & 1;
  int mt0 = blockIdx.x * 8 + ww * 4;
  int nt0 = blockIdx.y * 8 + wc * 4;
  const uint4* B = (const uint4*)Bp + (size_t)dir * 48 * KT * 64;
  const int arow = lane & 15;
  const int k0b = ((lane >> 4) << 3);

  f32x4 acc[4][4] = {};
#pragma unroll
  for (int kt = 0; kt < KT; ++kt) {
    int k0 = kt * 32 + k0b;
    bf16x8 a[4], b[4];
#pragma unroll
    for (int i = 0; i < 4; ++i) {
      int grow = t0 * 64 + (mt0 + i) * 16 + arow;
      if (LAYER == 0) {
        int gr = dir ? revrow(grow) : grow;
        const float4* s = (const float4*)(x + (size_t)gr * 256 + k0);
        a[i] = cvt8(s[0], s[1]);
      } else {
        const unsigned short* base; int r2 = grow, kk = k0;
        if (k0 < 256) { base = dir ? bs0 : fs0; }
        else          { base = dir ? fs0 : bs0; r2 = revrow(grow); kk = k0 - 256; }
        a[i] = *(const bf16x8*)(base + (size_t)r2 * 256 + kk);
      }
    }
#pragma unroll
    for (int j = 0; j < 4; ++j) b[j] = ld_frag(B + ((size_t)(nt0 + j) * KT + kt) * 64 + lane);
#pragma unroll
    for (int i = 0; i < 4; ++i)
#pragma unroll
      for (int j = 0; j < 4; ++j)
        acc[i][j] = __builtin_amdgcn_mfma_f32_16x16x32_bf16(a[i], b[j], acc[i][j], 0, 0, 0);
  }

  const float* bias = dir ? bias_bw : bias_fw;
  f32x4* C = Xg + (size_t)dir * (chunkT * 4) * 48 * 64;
#pragma unroll
  for (int j = 0; j < 4; ++j) {
    int ct = nt0 + j;
    int col = ct * 16 + (lane & 15);
    int g = col >> 8, cc = col & 255;
    float bv = ((g == 1) ? S_C : S_RZ) * bias[g * 256 + cc];
#pragma unroll
    for (int i = 0; i < 4; ++i) {
      int rt = blockIdx.x * 8 + ww * 4 + i;
      f32x4 v = acc[i][j];
      v[0] += bv; v[1] += bv; v[2] += bv; v[3] += bv;
      C[((size_t)rt * 48 + ct) * 64 + lane] = v;
    }
  }
}

// ---------------- persistent recurrent GRU kernel (one layer, both dirs, chunked) -----
// grid (4, 2), 512 threads = 8 waves. Whrz in physical a0..a127; Whc in LDS.
// Swizzle now folds row bit 3 into addr bit 5: epilogue b16 write groups at rows
// {r,r+4,r+8,r+12} land on disjoint bank sets (was 4-way conflict), reads stay <=2-way.
template<int LAYER>
__global__ __launch_bounds__(512) __attribute__((amdgpu_waves_per_eu(2, 2)))
void gru_kernel(const f32x4* __restrict__ Xg,
                const uint4* __restrict__ whrz_fw, const uint4* __restrict__ whrz_bw, // [32][8][64]
                const uint4* __restrict__ whc_fw,  const uint4* __restrict__ whc_bw,  // [16][8][64]
                unsigned short* __restrict__ sfw_bf, unsigned short* __restrict__ sbw_bf,
                float* __restrict__ out,
                float* __restrict__ hstate, float* __restrict__ dout_h,
                int t0, int chunkT)
{
  const int dir = blockIdx.y;
  const int bx = blockIdx.x;
  const int row0 = bx * 16;
  const int tid = threadIdx.x;
  const int lane = tid & 63;
  const int w = tid >> 6;               // 0..7

  // hx: [rh bf16 swizzled 8KB][h bf16 swizzled 8KB] — h = rh_addr + 8192 (offset imm)
  __shared__ __align__(16) unsigned short hx[2 * 16 * 256];
  __shared__ __align__(16) uint4 wc_lds[16 * 8 * 64];       // Whc B-fragments (128 KB)

  const uint4* whrzp = dir ? whrz_bw : whrz_fw;
  const uint4* whcp  = dir ? whc_bw  : whc_fw;

  for (int i = tid; i < 16 * 8 * 64; i += 512) wc_lds[i] = whcp[i];

  LOADF(0, 0, 1, 2, 3);     LOADF(1, 4, 5, 6, 7);     LOADF(2, 8, 9, 10, 11);   LOADF(3, 12, 13, 14, 15);
  LOADF(4, 16, 17, 18, 19); LOADF(5, 20, 21, 22, 23); LOADF(6, 24, 25, 26, 27); LOADF(7, 28, 29, 30, 31);
  LOADF(8, 32, 33, 34, 35); LOADF(9, 36, 37, 38, 39); LOADF(10, 40, 41, 42, 43); LOADF(11, 44, 45, 46, 47);
  LOADF(12, 48, 49, 50, 51); LOADF(13, 52, 53, 54, 55); LOADF(14, 56, 57, 58, 59); LOADF(15, 60, 61, 62, 63);
  LOADF(16, 64, 65, 66, 67); LOADF(17, 68, 69, 70, 71); LOADF(18, 72, 73, 74, 75); LOADF(19, 76, 77, 78, 79);
  LOADF(20, 80, 81, 82, 83); LOADF(21, 84, 85, 86, 87); LOADF(22, 88, 89, 90, 91); LOADF(23, 92, 93, 94, 95);
  LOADF(24, 96, 97, 98, 99); LOADF(25, 100, 101, 102, 103); LOADF(26, 104, 105, 106, 107); LOADF(27, 108, 109, 110, 111);
  LOADF(28, 112, 113, 114, 115); LOADF(29, 116, 117, 118, 119); LOADF(30, 120, 121, 122, 123); LOADF(31, 124, 125, 126, 127);

  const int ccol = lane & 15;
  const int crow = ((lane >> 4) << 2);     // 0,4,8,12

// swizzle: bits 4-6 ^= row[0:2], bit 5 ^= row[3]  (bijective per row; writes 2-way)
#define SWZ(rr, cb) ((rr) * 512 + ((((cb) & ~15) ^ (((rr) & 7) << 4) ^ (((rr) & 8) << 2)) | ((cb) & 15)))

  float* hst = hstate + (size_t)(dir * 4 + bx) * 4096;
  for (int i = tid; i < 16 * 256; i += 512) {
    float v = (t0 == 0) ? 0.0f : hst[i];
    int rr = i >> 8, cc = i & 255;
    *(unsigned short*)((char*)hx + 8192 + SWZ(rr, cc * 2)) = f2bf(v);
  }
  float hreg[2][4];
#pragma unroll
  for (int j = 0; j < 2; ++j)
#pragma unroll
    for (int r = 0; r < 4; ++r) {
      int rr = crow + r, c = (w * 2 + j) * 16 + ccol;
      hreg[j][r] = (t0 == 0) ? 0.0f : hst[rr * 256 + c];
    }
  __syncthreads();

  const f32x4* XgD = Xg + (size_t)dir * (chunkT * 4) * 48 * 64;
  unsigned short* sp_bf = dir ? sbw_bf : sfw_bf;
  const int coff = dir ? 256 : 0;
  const int ardbase = (lane & 15) * 512;
  const int arxor = ((lane & 7) << 4) ^ ((lane & 8) << 2);
  const int afc = ((lane >> 4) << 4);

  // hoisted LDS fragment-read addresses (loop-invariant; rh at +0, h at +8192)
  const int ra0 = ardbase + ((0 * 64 + afc) ^ arxor);
  const int ra1 = ardbase + ((1 * 64 + afc) ^ arxor);
  const int ra2 = ardbase + ((2 * 64 + afc) ^ arxor);
  const int ra3 = ardbase + ((3 * 64 + afc) ^ arxor);
  const int ra4 = ardbase + ((4 * 64 + afc) ^ arxor);
  const int ra5 = ardbase + ((5 * 64 + afc) ^ arxor);
  const int ra6 = ardbase + ((6 * 64 + afc) ^ arxor);
  const int ra7 = ardbase + ((7 * 64 + afc) ^ arxor);
#define HF(RA)  (*(const bf16x8*)((const char*)hx + 8192 + (RA)))
#define RHF(RA) (*(const bf16x8*)((const char*)hx + (RA)))

  // hoisted swizzled write addresses (rh at wa, h at wa+8192)
  const int cbj0 = ((w * 2 + 0) * 16 + ccol) * 2;
  const int cbj1 = ((w * 2 + 1) * 16 + ccol) * 2;
  const int wa00 = SWZ(crow + 0, cbj0), wa01 = SWZ(crow + 1, cbj0);
  const int wa02 = SWZ(crow + 2, cbj0), wa03 = SWZ(crow + 3, cbj0);
  const int wa10 = SWZ(crow + 0, cbj1), wa11 = SWZ(crow + 1, cbj1);
  const int wa12 = SWZ(crow + 2, cbj1), wa13 = SWZ(crow + 3, cbj1);

  // strided Xg pointers
  const size_t XSTEP = (size_t)4 * 48 * 64;
  const f32x4* pR = XgD + (size_t)bx * 48 * 64 + (size_t)(w * 2) * 64 + lane;
  const f32x4* pZ = pR + (size_t)32 * 64;
  const f32x4* pB = pR + (size_t)16 * 64;

  // strided output pointers
  unsigned short* pSp = sp_bf + ((size_t)(t0 * 64 + row0 + crow) * 256) + (w * 2) * 16 + ccol;
  const int g0 = (LAYER == 1 && dir) ? ((T_STEPS - 1 - t0) * 64 + row0) : (t0 * 64 + row0);
  float* pO = out ? out + ((size_t)(g0 + crow) * 512) + coff + (w * 2) * 16 + ccol : nullptr;
  float* pO2 = pO ? pO + 2 * 512 : nullptr;
  const long long OSTEP = (LAYER == 1 && dir) ? -(long long)64 * 512 : (long long)64 * 512;

  f32x4 zq = {0.0f, 0.0f, 0.0f, 0.0f};

  // prologue: step-0 Xg
  f32x4 xa0 = pR[0], xa1 = pR[64], xa2 = pZ[0], xa3 = pZ[64], xb0 = pB[0], xb1 = pB[64];

#pragma unroll 1
  for (int t = t0; t < t0 + chunkT; ++t) {
    // ---------- phase A: rz = h @ Whrz, weights from pinned AGPRs ----------
    f32x4 accA0, accA1, accA2, accA3;
    {
      bf16x8 af;
      af = HF(ra0);
      MFMA_AZ(accA0, af, 0, 3, zq);   MFMA_AZ(accA1, af, 32, 35, zq);
      MFMA_AZ(accA2, af, 64, 67, zq); MFMA_AZ(accA3, af, 96, 99, zq);
      af = HF(ra1);
      MFMA_A(accA0, af, 4, 7);    MFMA_A(accA1, af, 36, 39);
      MFMA_A(accA2, af, 68, 71);  MFMA_A(accA3, af, 100, 103);
      af = HF(ra2);
      MFMA_A(accA0, af, 8, 11);   MFMA_A(accA1, af, 40, 43);
      MFMA_A(accA2, af, 72, 75);  MFMA_A(accA3, af, 104, 107);
      af = HF(ra3);
      MFMA_A(accA0, af, 12, 15);  MFMA_A(accA1, af, 44, 47);
      MFMA_A(accA2, af, 76, 79);  MFMA_A(accA3, af, 108, 111);
      af = HF(ra4);
      MFMA_A(accA0, af, 16, 19);  MFMA_A(accA1, af, 48, 51);
      MFMA_A(accA2, af, 80, 83);  MFMA_A(accA3, af, 112, 115);
      af = HF(ra5);
      MFMA_A(accA0, af, 20, 23);  MFMA_A(accA1, af, 52, 55);
      MFMA_A(accA2, af, 84, 87);  MFMA_A(accA3, af, 116, 119);
      af = HF(ra6);
      MFMA_A(accA0, af, 24, 27);  MFMA_A(accA1, af, 56, 59);
      MFMA_A(accA2, af, 88, 91);  MFMA_A(accA3, af, 120, 123);
      af = HF(ra7);
      MFMA_A(accA0, af, 28, 31);  MFMA_A(accA1, af, 60, 63);
      MFMA_A(accA2, af, 92, 95);  MFMA_A(accA3, af, 124, 127);
    }
    ACCFENCE2(accA0, accA1);

    // epilogue A (r-gates): rh -> LDS via packed bf16 pairs, hoisted addresses
    {
      float rh0[4], rh1[4];
#pragma unroll
      for (int r = 0; r < 4; ++r) {
        float v0 = accA0[r] + xa0[r];
        rh0[r] = __builtin_amdgcn_rcpf(1.0f + __builtin_amdgcn_exp2f(v0)) * hreg[0][r];
        float v1 = accA1[r] + xa1[r];
        rh1[r] = __builtin_amdgcn_rcpf(1.0f + __builtin_amdgcn_exp2f(v1)) * hreg[1][r];
      }
      unsigned a01 = cvt_pk_bf16(rh0[0], rh0[1]);
      unsigned a23 = cvt_pk_bf16(rh0[2], rh0[3]);
      unsigned b01 = cvt_pk_bf16(rh1[0], rh1[1]);
      unsigned b23 = cvt_pk_bf16(rh1[2], rh1[3]);
      *(unsigned short*)((char*)hx + wa00) = (unsigned short)a01;
      *(unsigned short*)((char*)hx + wa01) = (unsigned short)(a01 >> 16);
      *(unsigned short*)((char*)hx + wa02) = (unsigned short)a23;
      *(unsigned short*)((char*)hx + wa03) = (unsigned short)(a23 >> 16);
      *(unsigned short*)((char*)hx + wa10) = (unsigned short)b01;
      *(unsigned short*)((char*)hx + wa11) = (unsigned short)(b01 >> 16);
      *(unsigned short*)((char*)hx + wa12) = (unsigned short)b23;
      *(unsigned short*)((char*)hx + wa13) = (unsigned short)(b23 >> 16);
    }
    asm volatile("s_waitcnt lgkmcnt(0)" ::: "memory", ACLB);
    __builtin_amdgcn_s_barrier();

    // ---------- phase B ----------
    ACCFENCE2(accA2, accA3);
    float zreg[2][4];
#pragma unroll
    for (int r = 0; r < 4; ++r) {
      zreg[0][r] = __builtin_amdgcn_rcpf(1.0f + __builtin_amdgcn_exp2f(accA2[r] + xa2[r]));
      zreg[1][r] = __builtin_amdgcn_rcpf(1.0f + __builtin_amdgcn_exp2f(accA3[r] + xa3[r]));
    }

    // cand matmul — 4 kt-split chains, zero-quad C-in
    f32x4 accB0a, accB0b, accB1a, accB1b;
    {
      bf16x8 a;
      a = RHF(ra0);
      MFMA_VZ(accB0a, a, *(const bf16x8*)&wc_lds[((size_t)(w * 2 + 0) * 8 + 0) * 64 + lane], zq);
      MFMA_VZ(accB1a, a, *(const bf16x8*)&wc_lds[((size_t)(w * 2 + 1) * 8 + 0) * 64 + lane], zq);
      a = RHF(ra1);
      MFMA_V(accB0a, a, *(const bf16x8*)&wc_lds[((size_t)(w * 2 + 0) * 8 + 1) * 64 + lane]);
      MFMA_V(accB1a, a, *(const bf16x8*)&wc_lds[((size_t)(w * 2 + 1) * 8 + 1) * 64 + lane]);
      a = RHF(ra2);
      MFMA_V(accB0a, a, *(const bf16x8*)&wc_lds[((size_t)(w * 2 + 0) * 8 + 2) * 64 + lane]);
      MFMA_V(accB1a, a, *(const bf16x8*)&wc_lds[((size_t)(w * 2 + 1) * 8 + 2) * 64 + lane]);
      a = RHF(ra3);
      MFMA_V(accB0a, a, *(const bf16x8*)&wc_lds[((size_t)(w * 2 + 0) * 8 + 3) * 64 + lane]);
      MFMA_V(accB1a, a, *(const bf16x8*)&wc_lds[((size_t)(w * 2 + 1) * 8 + 3) * 64 + lane]);
      a = RHF(ra4);
      MFMA_VZ(accB0b, a, *(const bf16x8*)&wc_lds[((size_t)(w * 2 + 0) * 8 + 4) * 64 + lane], zq);
      MFMA_VZ(accB1b, a, *(const bf16x8*)&wc_lds[((size_t)(w * 2 + 1) * 8 + 4) * 64 + lane], zq);
      a = RHF(ra5);
      MFMA_V(accB0b, a, *(const bf16x8*)&wc_lds[((size_t)(w * 2 + 0) * 8 + 5) * 64 + lane]);
      MFMA_V(accB1b, a, *(const bf16x8*)&wc_lds[((size_t)(w * 2 + 1) * 8 + 5) * 64 + lane]);
      a = RHF(ra6);
      MFMA_V(accB0b, a, *(const bf16x8*)&wc_lds[((size_t)(w * 2 + 0) * 8 + 6) * 64 + lane]);
      MFMA_V(accB1b, a, *(const bf16x8*)&wc_lds[((size_t)(w * 2 + 1) * 8 + 6) * 64 + lane]);
      a = RHF(ra7);
      MFMA_V(accB0b, a, *(const bf16x8*)&wc_lds[((size_t)(w * 2 + 0) * 8 + 7) * 64 + lane]);
      MFMA_V(accB1b, a, *(const bf16x8*)&wc_lds[((size_t)(w * 2 + 1) * 8 + 7) * 64 + lane]);
    }
    // capture current-step cand x-parts, then prefetch next step (padded buffer)
    f32x4 cb0 = xb0, cb1 = xb1;
    pR += XSTEP; pZ += XSTEP; pB += XSTEP;
    xa0 = pR[0]; xa1 = pR[64]; xa2 = pZ[0]; xa3 = pZ[64]; xb0 = pB[0]; xb1 = pB[64];

    ACCFENCE4(accB0a, accB0b, accB1a, accB1b);
    f32x4 accB0 = accB0a + accB0b;
    f32x4 accB1 = accB1a + accB1b;

#pragma unroll
    for (int j = 0; j < 2; ++j) {
      f32x4 ac = j ? accB1 : accB0;
      f32x4 xv = j ? cb1 : cb0;
      float hn[4];
#pragma unroll
      for (int r = 0; r < 4; ++r) {
        float v = ac[r] + xv[r];
        float cand = __builtin_amdgcn_rcpf(1.0f + __builtin_amdgcn_exp2f(v)) * 2.0f - 1.0f;
        hn[r] = cand + zreg[j][r] * (hreg[j][r] - cand);
        hreg[j][r] = hn[r];
      }
      unsigned p01 = cvt_pk_bf16(hn[0], hn[1]);
      unsigned p23 = cvt_pk_bf16(hn[2], hn[3]);
      int wA = j ? wa10 : wa00, wB = j ? wa11 : wa01;
      int wC = j ? wa12 : wa02, wD = j ? wa13 : wa03;
      *(unsigned short*)((char*)hx + 8192 + wA) = (unsigned short)p01;
      *(unsigned short*)((char*)hx + 8192 + wB) = (unsigned short)(p01 >> 16);
      *(unsigned short*)((char*)hx + 8192 + wC) = (unsigned short)p23;
      *(unsigned short*)((char*)hx + 8192 + wD) = (unsigned short)(p23 >> 16);
      if (LAYER == 0) {
        pSp[(size_t)j * 16 + 0 * 256] = (unsigned short)p01;
        pSp[(size_t)j * 16 + 1 * 256] = (unsigned short)(p01 >> 16);
        pSp[(size_t)j * 16 + 2 * 256] = (unsigned short)p23;
        pSp[(size_t)j * 16 + 3 * 256] = (unsigned short)(p23 >> 16);
      } else {
        pO[(size_t)j * 16 + 0 * 512] = hn[0];
        pO[(size_t)j * 16 + 1 * 512] = hn[1];
        pO2[(size_t)j * 16 + 0 * 512] = hn[2];
        pO2[(size_t)j * 16 + 1 * 512] = hn[3];
      }
    }
    if (LAYER == 0) pSp += (size_t)64 * 256;
    else { pO += OSTEP; pO2 += OSTEP; }

    asm volatile("s_waitcnt lgkmcnt(0)" ::: "memory", ACLB);
    __builtin_amdgcn_s_barrier();
  }

  // persist h; on last chunk also write fh/bh
#pragma unroll
  for (int j = 0; j < 2; ++j)
#pragma unroll
    for (int r = 0; r < 4; ++r) {
      int rr = crow + r, c = (w * 2 + j) * 16 + ccol;
      hst[rr * 256 + c] = hreg[j][r];
      if (t0 + chunkT == T_STEPS) {
        float* dst = dout_h + (dir ? 32768 : 0) + (size_t)LAYER * 16384;
        dst[(size_t)(row0 + rr) * 256 + c] = hreg[j][r];
      }
    }
}

__global__ void diag_kernel(float* out, float v) { out[0] = v; }

// --------------------------------------------------------------------------------------
extern "C" void kernel_launch(void* const* d_in, const int* in_sizes, int n_in,
                              void* d_out, int out_size, void* d_ws, size_t ws_size,
                              hipStream_t stream) {
  const float* x     = (const float*)d_in[0];
  const float* fw_W0 = (const float*)d_in[2];
  const float* fw_b0 = (const float*)d_in[3];
  const float* fw_W1 = (const float*)d_in[4];
  const float* fw_b1 = (const float*)d_in[5];
  const float* bw_W0 = (const float*)d_in[6];
  const float* bw_b0 = (const float*)d_in[7];
  const float* bw_W1 = (const float*)d_in[8];
  const float* bw_b1 = (const float*)d_in[9];

  char* ws = (char*)d_ws;
  size_t off = 0;
  auto alloc = [&](size_t bytes) -> char* {
    char* p = ws + off; off += (bytes + 255) & ~(size_t)255; return p;
  };
  unsigned short* Wx0p  = (unsigned short*)alloc(2ull * 48 * 8 * 64 * 8 * 2);
  unsigned short* Wx1p  = (unsigned short*)alloc(2ull * 48 * 16 * 64 * 8 * 2);
  unsigned short* Whrz0 = (unsigned short*)alloc(2ull * 32 * 8 * 64 * 8 * 2);
  unsigned short* Whc0  = (unsigned short*)alloc(2ull * 16 * 8 * 64 * 8 * 2);
  unsigned short* Whrz1 = (unsigned short*)alloc(2ull * 32 * 8 * 64 * 8 * 2);
  unsigned short* Whc1  = (unsigned short*)alloc(2ull * 16 * 8 * 64 * 8 * 2);
  unsigned short* fs0   = (unsigned short*)alloc((size_t)TB * 256 * 2);
  unsigned short* bs0   = (unsigned short*)alloc((size_t)TB * 256 * 2);
  float* hstate         = (float*)alloc(2ull * 4 * 16 * 256 * 4);

  const size_t XPAD = (size_t)4 * 48 * 64 * 16;
  int chunkT = 0;
  for (int ct = 512; ct >= 8; ct >>= 1) {
    if (off + (size_t)ct * 2 * 64 * 768 * 4 + XPAD <= ws_size) { chunkT = ct; break; }
  }
  float* out = (float*)d_out;
  if (chunkT == 0) {
    diag_kernel<<<1, 1, 0, stream>>>(out, 12345.0f);
    return;
  }
  f32x4* Xg = (f32x4*)alloc((size_t)chunkT * 2 * 64 * 768 * 4 + XPAD);
  float* dout_h = out + (size_t)TB * 512;

  auto packw = [&](const float* W, int rows, int kb, int ntl, int ktl, int mode, unsigned short* dst) {
    int total = ntl * ktl * 64;
    pack_w_kernel<<<(total + 255) / 256, 256, 0, stream>>>(W, rows, kb, ntl, ktl, mode, dst);
  };
  packw(fw_W0, 512, 0,   48, 8,  0, Wx0p);
  packw(bw_W0, 512, 0,   48, 8,  0, Wx0p + 48 * 8 * 64 * 8);
  packw(fw_W1, 768, 0,   48, 16, 0, Wx1p);
  packw(bw_W1, 768, 0,   48, 16, 0, Wx1p + 48 * 16 * 64 * 8);
  packw(fw_W0, 512, 256, 32, 8,  1, Whrz0);
  packw(bw_W0, 512, 256, 32, 8,  1, Whrz0 + 32 * 8 * 64 * 8);
  packw(fw_W0, 512, 256, 16, 8,  2, Whc0);
  packw(bw_W0, 512, 256, 16, 8,  2, Whc0 + 16 * 8 * 64 * 8);
  packw(fw_W1, 768, 512, 32, 8,  1, Whrz1);
  packw(bw_W1, 768, 512, 32, 8,  1, Whrz1 + 32 * 8 * 64 * 8);
  packw(fw_W1, 768, 512, 16, 8,  2, Whc1);
  packw(bw_W1, 768, 512, 16, 8,  2, Whc1 + 16 * 8 * 64 * 8);

  dim3 rgrid(4, 2);
  // layer 0
  for (int t0 = 0; t0 < T_STEPS; t0 += chunkT) {
    dim3 ggrid(chunkT / 2, 6, 2);
    gemm_xg_kernel<0><<<ggrid, 256, 0, stream>>>(x, nullptr, nullptr, Wx0p, fw_b0, bw_b0, Xg, t0, chunkT);
    gru_kernel<0><<<rgrid, 512, 0, stream>>>(Xg,
        (const uint4*)Whrz0, (const uint4*)(Whrz0 + 32 * 8 * 64 * 8),
        (const uint4*)Whc0,  (const uint4*)(Whc0 + 16 * 8 * 64 * 8),
        fs0, bs0, nullptr, hstate, dout_h, t0, chunkT);
  }
  // layer 1
  for (int t0 = 0; t0 < T_STEPS; t0 += chunkT) {
    dim3 ggrid(chunkT / 2, 6, 2);
    gemm_xg_kernel<1><<<ggrid, 256, 0, stream>>>(nullptr, fs0, bs0, Wx1p, fw_b1, bw_b1, Xg, t0, chunkT);
    gru_kernel<1><<<rgrid, 512, 0, stream>>>(Xg,
        (const uint4*)Whrz1, (const uint4*)(Whrz1 + 32 * 8 * 64 * 8),
        (const uint4*)Whc1,  (const uint4*)(Whc1 + 16 * 8 * 64 * 8),
        nullptr, nullptr, out, hstate, dout_h, t0, chunkT);
  }
}

// Round 14
// 2206.674 us; speedup vs baseline: 1.1986x; 1.1240x over previous
//
#include <hip/hip_runtime.h>
#include <hip/hip_bf16.h>

#define T_STEPS 512
#define BATCH 64
#define TB (T_STEPS * BATCH)   // 32768

typedef short bf16x8 __attribute__((ext_vector_type(8)));
typedef float f32x4 __attribute__((ext_vector_type(4)));

union FragU { uint4 u; bf16x8 v; };

static __device__ __forceinline__ bf16x8 ld_frag(const uint4* p) {
  FragU f; f.u = *p; return f.v;
}

static __device__ __forceinline__ unsigned short f2bf(float f) {
  unsigned u = __float_as_uint(f);
  return (unsigned short)((u + 0x7FFFu + ((u >> 16) & 1u)) >> 16);
}

// packed f32->bf16 (RNE), 1 inst per pair
static __device__ __forceinline__ unsigned cvt_pk_bf16(float lo, float hi) {
  unsigned r;
  asm("v_cvt_pk_bf16_f32 %0, %1, %2" : "=v"(r) : "v"(lo), "v"(hi));
  return r;
}

static __device__ __forceinline__ int revrow(int r) {
  int t = r >> 6, b = r & 63;
  return ((T_STEPS - 1 - t) << 6) | b;
}

#define S_RZ  (-1.4426950408889634f)
#define S_C   (-2.8853900817779268f)

// ---- explicit named-AGPR weight residency (round-8..13-validated) --------------------
#define AWR(N, x) asm volatile("v_accvgpr_write_b32 a" #N ", %0" :: "v"(x) : "a" #N)
#define LOADF(F, A0, A1, A2, A3) do { \
    const int c_ = (F) >> 3, kt_ = (F) & 7; \
    const int nt_ = (c_ < 2) ? (w * 2 + c_) : (14 + w * 2 + c_); \
    uint4 t = whrzp[((size_t)nt_ * 8 + kt_) * 64 + lane]; \
    AWR(A0, t.x); AWR(A1, t.y); AWR(A2, t.z); AWR(A3, t.w); } while (0)

#define MFMA_A(acc, va, B0, B3) \
  asm volatile("v_mfma_f32_16x16x32_bf16 %0, %1, a[" #B0 ":" #B3 "], %0" \
               : "+v"(acc) : "v"(va))
#define MFMA_AZ(acc, va, B0, B3, zq) \
  asm volatile("v_mfma_f32_16x16x32_bf16 %0, %1, a[" #B0 ":" #B3 "], %2" \
               : "=&v"(acc) : "v"(va), "v"(zq))
#define MFMA_V(acc, va, vb) \
  asm volatile("v_mfma_f32_16x16x32_bf16 %0, %1, %2, %0" \
               : "+v"(acc) : "v"(va), "v"(vb))
#define MFMA_VZ(acc, va, vb, zq) \
  asm volatile("v_mfma_f32_16x16x32_bf16 %0, %1, %2, %3" \
               : "=&v"(acc) : "v"(va), "v"(vb), "v"(zq))
#define ACCFENCE2(a, b) asm volatile("s_nop 7\n\ts_nop 7" : "+v"(a), "+v"(b))

#define ACLB \
  "a0","a1","a2","a3","a4","a5","a6","a7","a8","a9","a10","a11","a12","a13","a14","a15", \
  "a16","a17","a18","a19","a20","a21","a22","a23","a24","a25","a26","a27","a28","a29","a30","a31", \
  "a32","a33","a34","a35","a36","a37","a38","a39","a40","a41","a42","a43","a44","a45","a46","a47", \
  "a48","a49","a50","a51","a52","a53","a54","a55","a56","a57","a58","a59","a60","a61","a62","a63", \
  "a64","a65","a66","a67","a68","a69","a70","a71","a72","a73","a74","a75","a76","a77","a78","a79", \
  "a80","a81","a82","a83","a84","a85","a86","a87","a88","a89","a90","a91","a92","a93","a94","a95", \
  "a96","a97","a98","a99","a100","a101","a102","a103","a104","a105","a106","a107","a108","a109","a110","a111", \
  "a112","a113","a114","a115","a116","a117","a118","a119","a120","a121","a122","a123","a124","a125","a126","a127"

// ---------------- pack weights into MFMA B-fragment layout (with gate pre-scaling) ----
__global__ void pack_w_kernel(const float* __restrict__ W, int rows, int k_base,
                              int n_tiles, int k_tiles, int mode,
                              unsigned short* __restrict__ dst) {
  int gid = blockIdx.x * blockDim.x + threadIdx.x;
  int total = n_tiles * k_tiles * 64;
  if (gid >= total) return;
  int lane = gid & 63;
  int fi = gid >> 6;
  int kt = fi % k_tiles;
  int nt = fi / k_tiles;
  int n = nt * 16 + (lane & 15);
  int g, col; float s;
  if (mode == 0)      { g = n >> 8;            col = n & 255; s = (g == 1) ? S_C : S_RZ; }
  else if (mode == 1) { g = (n < 256) ? 0 : 2; col = n & 255; s = S_RZ; }
  else                { g = 1;                 col = n;       s = S_C; }
  int k0 = k_base + kt * 32 + ((lane >> 4) << 3);
  const float* src = W + ((size_t)g * rows + k0) * 256 + col;
  unsigned short v[8];
#pragma unroll
  for (int j = 0; j < 8; ++j) v[j] = f2bf(src[(size_t)j * 256] * s);
  uint4 o;
  o.x = v[0] | ((unsigned)v[1] << 16);
  o.y = v[2] | ((unsigned)v[3] << 16);
  o.z = v[4] | ((unsigned)v[5] << 16);
  o.w = v[6] | ((unsigned)v[7] << 16);
  ((uint4*)dst)[gid] = o;
}

static __device__ __forceinline__ bf16x8 cvt8(float4 f0, float4 f1) {
  uint4 o;
  o.x = f2bf(f0.x) | ((unsigned)f2bf(f0.y) << 16);
  o.y = f2bf(f0.z) | ((unsigned)f2bf(f0.w) << 16);
  o.z = f2bf(f1.x) | ((unsigned)f2bf(f1.y) << 16);
  o.w = f2bf(f1.z) | ((unsigned)f2bf(f1.w) << 16);
  FragU f; f.u = o; return f.v;
}

// ---------------- Xg GEMM (chunked): writes C-fragment tile layout --------------------
template<int LAYER>
__global__ __launch_bounds__(256)
void gemm_xg_kernel(const float* __restrict__ x,
                    const unsigned short* __restrict__ fs0,
                    const unsigned short* __restrict__ bs0,
                    const unsigned short* __restrict__ Bp,
                    const float* __restrict__ bias_fw,
                    const float* __restrict__ bias_bw,
                    f32x4* __restrict__ Xg, int t0, int chunkT)
{
  constexpr int KT = (LAYER == 0) ? 8 : 16;
  int dir = blockIdx.z;
  int lane = threadIdx.x & 63;
  int w = threadIdx.x >> 6;
  int ww = w >> 1, wc = w & 1;
  int mt0 = blockIdx.x * 8 + ww * 4;
  int nt0 = blockIdx.y * 8 + wc * 4;
  const uint4* B = (const uint4*)Bp + (size_t)dir * 48 * KT * 64;
  const int arow = lane & 15;
  const int k0b = ((lane >> 4) << 3);

  f32x4 acc[4][4] = {};
#pragma unroll
  for (int kt = 0; kt < KT; ++kt) {
    int k0 = kt * 32 + k0b;
    bf16x8 a[4], b[4];
#pragma unroll
    for (int i = 0; i < 4; ++i) {
      int grow = t0 * 64 + (mt0 + i) * 16 + arow;
      if (LAYER == 0) {
        int gr = dir ? revrow(grow) : grow;
        const float4* s = (const float4*)(x + (size_t)gr * 256 + k0);
        a[i] = cvt8(s[0], s[1]);
      } else {
        const unsigned short* base; int r2 = grow, kk = k0;
        if (k0 < 256) { base = dir ? bs0 : fs0; }
        else          { base = dir ? fs0 : bs0; r2 = revrow(grow); kk = k0 - 256; }
        a[i] = *(const bf16x8*)(base + (size_t)r2 * 256 + kk);
      }
    }
#pragma unroll
    for (int j = 0; j < 4; ++j) b[j] = ld_frag(B + ((size_t)(nt0 + j) * KT + kt) * 64 + lane);
#pragma unroll
    for (int i = 0; i < 4; ++i)
#pragma unroll
      for (int j = 0; j < 4; ++j)
        acc[i][j] = __builtin_amdgcn_mfma_f32_16x16x32_bf16(a[i], b[j], acc[i][j], 0, 0, 0);
  }

  const float* bias = dir ? bias_bw : bias_fw;
  f32x4* C = Xg + (size_t)dir * (chunkT * 4) * 48 * 64;
#pragma unroll
  for (int j = 0; j < 4; ++j) {
    int ct = nt0 + j;
    int col = ct * 16 + (lane & 15);
    int g = col >> 8, cc = col & 255;
    float bv = ((g == 1) ? S_C : S_RZ) * bias[g * 256 + cc];
#pragma unroll
    for (int i = 0; i < 4; ++i) {
      int rt = blockIdx.x * 8 + ww * 4 + i;
      f32x4 v = acc[i][j];
      v[0] += bv; v[1] += bv; v[2] += bv; v[3] += bv;
      C[((size_t)rt * 48 + ct) * 64 + lane] = v;
    }
  }
}

// ---------------- persistent recurrent GRU kernel (one layer, both dirs, chunked) -----
// grid (4, 2), 512 threads = 8 waves. Whrz in physical a0..a127; Whc in LDS.
// Phase-balanced schedule: phase A = r only (16 MFMA); phase B = z (register-only
// AGPR MFMAs, overlapping rh+wc LDS reads) + cand. h-fragments carried in registers
// across barrier 1 and reused for rh fragments.
template<int LAYER>
__global__ __launch_bounds__(512) __attribute__((amdgpu_waves_per_eu(2, 2)))
void gru_kernel(const f32x4* __restrict__ Xg,
                const uint4* __restrict__ whrz_fw, const uint4* __restrict__ whrz_bw, // [32][8][64]
                const uint4* __restrict__ whc_fw,  const uint4* __restrict__ whc_bw,  // [16][8][64]
                unsigned short* __restrict__ sfw_bf, unsigned short* __restrict__ sbw_bf,
                float* __restrict__ out,
                float* __restrict__ hstate, float* __restrict__ dout_h,
                int t0, int chunkT)
{
  const int dir = blockIdx.y;
  const int bx = blockIdx.x;
  const int row0 = bx * 16;
  const int tid = threadIdx.x;
  const int lane = tid & 63;
  const int w = tid >> 6;               // 0..7

  // hx: [rh bf16 swizzled 8KB][h bf16 swizzled 8KB] — h = rh_addr + 8192 (offset imm)
  __shared__ __align__(16) unsigned short hx[2 * 16 * 256];
  __shared__ __align__(16) uint4 wc_lds[16 * 8 * 64];       // Whc B-fragments (128 KB)

  const uint4* whrzp = dir ? whrz_bw : whrz_fw;
  const uint4* whcp  = dir ? whc_bw  : whc_fw;

  for (int i = tid; i < 16 * 8 * 64; i += 512) wc_lds[i] = whcp[i];

  LOADF(0, 0, 1, 2, 3);     LOADF(1, 4, 5, 6, 7);     LOADF(2, 8, 9, 10, 11);   LOADF(3, 12, 13, 14, 15);
  LOADF(4, 16, 17, 18, 19); LOADF(5, 20, 21, 22, 23); LOADF(6, 24, 25, 26, 27); LOADF(7, 28, 29, 30, 31);
  LOADF(8, 32, 33, 34, 35); LOADF(9, 36, 37, 38, 39); LOADF(10, 40, 41, 42, 43); LOADF(11, 44, 45, 46, 47);
  LOADF(12, 48, 49, 50, 51); LOADF(13, 52, 53, 54, 55); LOADF(14, 56, 57, 58, 59); LOADF(15, 60, 61, 62, 63);
  LOADF(16, 64, 65, 66, 67); LOADF(17, 68, 69, 70, 71); LOADF(18, 72, 73, 74, 75); LOADF(19, 76, 77, 78, 79);
  LOADF(20, 80, 81, 82, 83); LOADF(21, 84, 85, 86, 87); LOADF(22, 88, 89, 90, 91); LOADF(23, 92, 93, 94, 95);
  LOADF(24, 96, 97, 98, 99); LOADF(25, 100, 101, 102, 103); LOADF(26, 104, 105, 106, 107); LOADF(27, 108, 109, 110, 111);
  LOADF(28, 112, 113, 114, 115); LOADF(29, 116, 117, 118, 119); LOADF(30, 120, 121, 122, 123); LOADF(31, 124, 125, 126, 127);

  const int ccol = lane & 15;
  const int crow = ((lane >> 4) << 2);     // 0,4,8,12

// swizzle: bits 4-6 ^= row[0:2], bit 5 ^= row[3]
#define SWZ(rr, cb) ((rr) * 512 + ((((cb) & ~15) ^ (((rr) & 7) << 4) ^ (((rr) & 8) << 2)) | ((cb) & 15)))

  float* hst = hstate + (size_t)(dir * 4 + bx) * 4096;
  for (int i = tid; i < 16 * 256; i += 512) {
    float v = (t0 == 0) ? 0.0f : hst[i];
    int rr = i >> 8, cc = i & 255;
    *(unsigned short*)((char*)hx + 8192 + SWZ(rr, cc * 2)) = f2bf(v);
  }
  float hreg[2][4];
#pragma unroll
  for (int j = 0; j < 2; ++j)
#pragma unroll
    for (int r = 0; r < 4; ++r) {
      int rr = crow + r, c = (w * 2 + j) * 16 + ccol;
      hreg[j][r] = (t0 == 0) ? 0.0f : hst[rr * 256 + c];
    }
  __syncthreads();

  const f32x4* XgD = Xg + (size_t)dir * (chunkT * 4) * 48 * 64;
  unsigned short* sp_bf = dir ? sbw_bf : sfw_bf;
  const int coff = dir ? 256 : 0;
  const int ardbase = (lane & 15) * 512;
  const int arxor = ((lane & 7) << 4) ^ ((lane & 8) << 2);
  const int afc = ((lane >> 4) << 4);

  const int ra0 = ardbase + ((0 * 64 + afc) ^ arxor);
  const int ra1 = ardbase + ((1 * 64 + afc) ^ arxor);
  const int ra2 = ardbase + ((2 * 64 + afc) ^ arxor);
  const int ra3 = ardbase + ((3 * 64 + afc) ^ arxor);
  const int ra4 = ardbase + ((4 * 64 + afc) ^ arxor);
  const int ra5 = ardbase + ((5 * 64 + afc) ^ arxor);
  const int ra6 = ardbase + ((6 * 64 + afc) ^ arxor);
  const int ra7 = ardbase + ((7 * 64 + afc) ^ arxor);
#define HF(RA)  (*(const bf16x8*)((const char*)hx + 8192 + (RA)))
#define RHF(RA) (*(const bf16x8*)((const char*)hx + (RA)))

  const int cbj0 = ((w * 2 + 0) * 16 + ccol) * 2;
  const int cbj1 = ((w * 2 + 1) * 16 + ccol) * 2;
  const int wa00 = SWZ(crow + 0, cbj0), wa01 = SWZ(crow + 1, cbj0);
  const int wa02 = SWZ(crow + 2, cbj0), wa03 = SWZ(crow + 3, cbj0);
  const int wa10 = SWZ(crow + 0, cbj1), wa11 = SWZ(crow + 1, cbj1);
  const int wa12 = SWZ(crow + 2, cbj1), wa13 = SWZ(crow + 3, cbj1);

  const size_t XSTEP = (size_t)4 * 48 * 64;
  const f32x4* pR = XgD + (size_t)bx * 48 * 64 + (size_t)(w * 2) * 64 + lane;
  const f32x4* pZ = pR + (size_t)32 * 64;
  const f32x4* pB = pR + (size_t)16 * 64;

  unsigned short* pSp = sp_bf + ((size_t)(t0 * 64 + row0 + crow) * 256) + (w * 2) * 16 + ccol;
  const int g0 = (LAYER == 1 && dir) ? ((T_STEPS - 1 - t0) * 64 + row0) : (t0 * 64 + row0);
  float* pO = out ? out + ((size_t)(g0 + crow) * 512) + coff + (w * 2) * 16 + ccol : nullptr;
  float* pO2 = pO ? pO + 2 * 512 : nullptr;
  const long long OSTEP = (LAYER == 1 && dir) ? -(long long)64 * 512 : (long long)64 * 512;

  f32x4 zq = {0.0f, 0.0f, 0.0f, 0.0f};

  // prologue: prefetch only the r-part Xg for step 0
  f32x4 xa0 = pR[0], xa1 = pR[64];

#pragma unroll 1
  for (int t = t0; t < t0 + chunkT; ++t) {
    // ---------- phase A: r = h @ Whr (16 MFMAs; h-frags kept in registers) ----------
    bf16x8 hf0 = HF(ra0), hf1 = HF(ra1), hf2 = HF(ra2), hf3 = HF(ra3);
    bf16x8 hf4 = HF(ra4), hf5 = HF(ra5), hf6 = HF(ra6), hf7 = HF(ra7);
    f32x4 accA0, accA1;
    MFMA_AZ(accA0, hf0, 0, 3, zq);   MFMA_AZ(accA1, hf0, 32, 35, zq);
    MFMA_A(accA0, hf1, 4, 7);    MFMA_A(accA1, hf1, 36, 39);
    MFMA_A(accA0, hf2, 8, 11);   MFMA_A(accA1, hf2, 40, 43);
    MFMA_A(accA0, hf3, 12, 15);  MFMA_A(accA1, hf3, 44, 47);
    MFMA_A(accA0, hf4, 16, 19);  MFMA_A(accA1, hf4, 48, 51);
    MFMA_A(accA0, hf5, 20, 23);  MFMA_A(accA1, hf5, 52, 55);
    MFMA_A(accA0, hf6, 24, 27);  MFMA_A(accA1, hf6, 56, 59);
    MFMA_A(accA0, hf7, 28, 31);  MFMA_A(accA1, hf7, 60, 63);
    ACCFENCE2(accA0, accA1);

    // epilogue A (r-gates): rh -> LDS via packed bf16 pairs
    {
      float rh0[4], rh1[4];
#pragma unroll
      for (int r = 0; r < 4; ++r) {
        float v0 = accA0[r] + xa0[r];
        rh0[r] = __builtin_amdgcn_rcpf(1.0f + __builtin_amdgcn_exp2f(v0)) * hreg[0][r];
        float v1 = accA1[r] + xa1[r];
        rh1[r] = __builtin_amdgcn_rcpf(1.0f + __builtin_amdgcn_exp2f(v1)) * hreg[1][r];
      }
      unsigned a01 = cvt_pk_bf16(rh0[0], rh0[1]);
      unsigned a23 = cvt_pk_bf16(rh0[2], rh0[3]);
      unsigned b01 = cvt_pk_bf16(rh1[0], rh1[1]);
      unsigned b23 = cvt_pk_bf16(rh1[2], rh1[3]);
      *(unsigned short*)((char*)hx + wa00) = (unsigned short)a01;
      *(unsigned short*)((char*)hx + wa01) = (unsigned short)(a01 >> 16);
      *(unsigned short*)((char*)hx + wa02) = (unsigned short)a23;
      *(unsigned short*)((char*)hx + wa03) = (unsigned short)(a23 >> 16);
      *(unsigned short*)((char*)hx + wa10) = (unsigned short)b01;
      *(unsigned short*)((char*)hx + wa11) = (unsigned short)(b01 >> 16);
      *(unsigned short*)((char*)hx + wa12) = (unsigned short)b23;
      *(unsigned short*)((char*)hx + wa13) = (unsigned short)(b23 >> 16);
    }
    asm volatile("s_waitcnt lgkmcnt(0)" ::: "memory", ACLB);
    __builtin_amdgcn_s_barrier();

    // ---------- phase B ----------
    // JIT Xg loads for z and cand (covered by the register-only z-MFMA block)
    f32x4 xz0 = pZ[0], xz1 = pZ[64], xb0 = pB[0], xb1 = pB[64];

    // z = h @ Whz — register-only MFMAs (AGPR weights, carried h-frags);
    // rh + wc LDS reads issue in their shadow
    f32x4 accZ0, accZ1;
    MFMA_AZ(accZ0, hf0, 64, 67, zq);  MFMA_AZ(accZ1, hf0, 96, 99, zq);
    MFMA_A(accZ0, hf1, 68, 71);   MFMA_A(accZ1, hf1, 100, 103);
    MFMA_A(accZ0, hf2, 72, 75);   MFMA_A(accZ1, hf2, 104, 107);
    MFMA_A(accZ0, hf3, 76, 79);   MFMA_A(accZ1, hf3, 108, 111);
    MFMA_A(accZ0, hf4, 80, 83);   MFMA_A(accZ1, hf4, 112, 115);
    MFMA_A(accZ0, hf5, 84, 87);   MFMA_A(accZ1, hf5, 116, 119);
    MFMA_A(accZ0, hf6, 88, 91);   MFMA_A(accZ1, hf6, 120, 123);
    MFMA_A(accZ0, hf7, 92, 95);   MFMA_A(accZ1, hf7, 124, 127);

    // reload fragment registers with rh (latency covered by z epilogue)
    hf0 = RHF(ra0); hf1 = RHF(ra1); hf2 = RHF(ra2); hf3 = RHF(ra3);
    hf4 = RHF(ra4); hf5 = RHF(ra5); hf6 = RHF(ra6); hf7 = RHF(ra7);

    ACCFENCE2(accZ0, accZ1);
    float zreg[2][4];
#pragma unroll
    for (int r = 0; r < 4; ++r) {
      zreg[0][r] = __builtin_amdgcn_rcpf(1.0f + __builtin_amdgcn_exp2f(accZ0[r] + xz0[r]));
      zreg[1][r] = __builtin_amdgcn_rcpf(1.0f + __builtin_amdgcn_exp2f(accZ1[r] + xz1[r]));
    }

    // cand = (r*h) @ Whc — wc streamed from LDS
    f32x4 accB0, accB1;
    MFMA_VZ(accB0, hf0, *(const bf16x8*)&wc_lds[((size_t)(w * 2 + 0) * 8 + 0) * 64 + lane], zq);
    MFMA_VZ(accB1, hf0, *(const bf16x8*)&wc_lds[((size_t)(w * 2 + 1) * 8 + 0) * 64 + lane], zq);
    MFMA_V(accB0, hf1, *(const bf16x8*)&wc_lds[((size_t)(w * 2 + 0) * 8 + 1) * 64 + lane]);
    MFMA_V(accB1, hf1, *(const bf16x8*)&wc_lds[((size_t)(w * 2 + 1) * 8 + 1) * 64 + lane]);
    MFMA_V(accB0, hf2, *(const bf16x8*)&wc_lds[((size_t)(w * 2 + 0) * 8 + 2) * 64 + lane]);
    MFMA_V(accB1, hf2, *(const bf16x8*)&wc_lds[((size_t)(w * 2 + 1) * 8 + 2) * 64 + lane]);
    MFMA_V(accB0, hf3, *(const bf16x8*)&wc_lds[((size_t)(w * 2 + 0) * 8 + 3) * 64 + lane]);
    MFMA_V(accB1, hf3, *(const bf16x8*)&wc_lds[((size_t)(w * 2 + 1) * 8 + 3) * 64 + lane]);
    MFMA_V(accB0, hf4, *(const bf16x8*)&wc_lds[((size_t)(w * 2 + 0) * 8 + 4) * 64 + lane]);
    MFMA_V(accB1, hf4, *(const bf16x8*)&wc_lds[((size_t)(w * 2 + 1) * 8 + 4) * 64 + lane]);
    MFMA_V(accB0, hf5, *(const bf16x8*)&wc_lds[((size_t)(w * 2 + 0) * 8 + 5) * 64 + lane]);
    MFMA_V(accB1, hf5, *(const bf16x8*)&wc_lds[((size_t)(w * 2 + 1) * 8 + 5) * 64 + lane]);
    MFMA_V(accB0, hf6, *(const bf16x8*)&wc_lds[((size_t)(w * 2 + 0) * 8 + 6) * 64 + lane]);
    MFMA_V(accB1, hf6, *(const bf16x8*)&wc_lds[((size_t)(w * 2 + 1) * 8 + 6) * 64 + lane]);
    MFMA_V(accB0, hf7, *(const bf16x8*)&wc_lds[((size_t)(w * 2 + 0) * 8 + 7) * 64 + lane]);
    MFMA_V(accB1, hf7, *(const bf16x8*)&wc_lds[((size_t)(w * 2 + 1) * 8 + 7) * 64 + lane]);
    ACCFENCE2(accB0, accB1);

#pragma unroll
    for (int j = 0; j < 2; ++j) {
      f32x4 ac = j ? accB1 : accB0;
      f32x4 xv = j ? xb1 : xb0;
      float hn[4];
#pragma unroll
      for (int r = 0; r < 4; ++r) {
        float v = ac[r] + xv[r];
        float cand = __builtin_amdgcn_rcpf(1.0f + __builtin_amdgcn_exp2f(v)) * 2.0f - 1.0f;
        hn[r] = cand + zreg[j][r] * (hreg[j][r] - cand);
        hreg[j][r] = hn[r];
      }
      unsigned p01 = cvt_pk_bf16(hn[0], hn[1]);
      unsigned p23 = cvt_pk_bf16(hn[2], hn[3]);
      int wA = j ? wa10 : wa00, wB = j ? wa11 : wa01;
      int wC = j ? wa12 : wa02, wD = j ? wa13 : wa03;
      *(unsigned short*)((char*)hx + 8192 + wA) = (unsigned short)p01;
      *(unsigned short*)((char*)hx + 8192 + wB) = (unsigned short)(p01 >> 16);
      *(unsigned short*)((char*)hx + 8192 + wC) = (unsigned short)p23;
      *(unsigned short*)((char*)hx + 8192 + wD) = (unsigned short)(p23 >> 16);
      if (LAYER == 0) {
        pSp[(size_t)j * 16 + 0 * 256] = (unsigned short)p01;
        pSp[(size_t)j * 16 + 1 * 256] = (unsigned short)(p01 >> 16);
        pSp[(size_t)j * 16 + 2 * 256] = (unsigned short)p23;
        pSp[(size_t)j * 16 + 3 * 256] = (unsigned short)(p23 >> 16);
      } else {
        pO[(size_t)j * 16 + 0 * 512] = hn[0];
        pO[(size_t)j * 16 + 1 * 512] = hn[1];
        pO2[(size_t)j * 16 + 0 * 512] = hn[2];
        pO2[(size_t)j * 16 + 1 * 512] = hn[3];
      }
    }
    if (LAYER == 0) pSp += (size_t)64 * 256;
    else { pO += OSTEP; pO2 += OSTEP; }

    // advance pointers; prefetch next step's r-part Xg (padded buffer)
    pR += XSTEP; pZ += XSTEP; pB += XSTEP;
    xa0 = pR[0]; xa1 = pR[64];

    asm volatile("s_waitcnt lgkmcnt(0)" ::: "memory", ACLB);
    __builtin_amdgcn_s_barrier();
  }

  // persist h; on last chunk also write fh/bh
#pragma unroll
  for (int j = 0; j < 2; ++j)
#pragma unroll
    for (int r = 0; r < 4; ++r) {
      int rr = crow + r, c = (w * 2 + j) * 16 + ccol;
      hst[rr * 256 + c] = hreg[j][r];
      if (t0 + chunkT == T_STEPS) {
        float* dst = dout_h + (dir ? 32768 : 0) + (size_t)LAYER * 16384;
        dst[(size_t)(row0 + rr) * 256 + c] = hreg[j][r];
      }
    }
}

__global__ void diag_kernel(float* out, float v) { out[0] = v; }

// --------------------------------------------------------------------------------------
extern "C" void kernel_launch(void* const* d_in, const int* in_sizes, int n_in,
                              void* d_out, int out_size, void* d_ws, size_t ws_size,
                              hipStream_t stream) {
  const float* x     = (const float*)d_in[0];
  const float* fw_W0 = (const float*)d_in[2];
  const float* fw_b0 = (const float*)d_in[3];
  const float* fw_W1 = (const float*)d_in[4];
  const float* fw_b1 = (const float*)d_in[5];
  const float* bw_W0 = (const float*)d_in[6];
  const float* bw_b0 = (const float*)d_in[7];
  const float* bw_W1 = (const float*)d_in[8];
  const float* bw_b1 = (const float*)d_in[9];

  char* ws = (char*)d_ws;
  size_t off = 0;
  auto alloc = [&](size_t bytes) -> char* {
    char* p = ws + off; off += (bytes + 255) & ~(size_t)255; return p;
  };
  unsigned short* Wx0p  = (unsigned short*)alloc(2ull * 48 * 8 * 64 * 8 * 2);
  unsigned short* Wx1p  = (unsigned short*)alloc(2ull * 48 * 16 * 64 * 8 * 2);
  unsigned short* Whrz0 = (unsigned short*)alloc(2ull * 32 * 8 * 64 * 8 * 2);
  unsigned short* Whc0  = (unsigned short*)alloc(2ull * 16 * 8 * 64 * 8 * 2);
  unsigned short* Whrz1 = (unsigned short*)alloc(2ull * 32 * 8 * 64 * 8 * 2);
  unsigned short* Whc1  = (unsigned short*)alloc(2ull * 16 * 8 * 64 * 8 * 2);
  unsigned short* fs0   = (unsigned short*)alloc((size_t)TB * 256 * 2);
  unsigned short* bs0   = (unsigned short*)alloc((size_t)TB * 256 * 2);
  float* hstate         = (float*)alloc(2ull * 4 * 16 * 256 * 4);

  const size_t XPAD = (size_t)4 * 48 * 64 * 16;
  int chunkT = 0;
  for (int ct = 512; ct >= 8; ct >>= 1) {
    if (off + (size_t)ct * 2 * 64 * 768 * 4 + XPAD <= ws_size) { chunkT = ct; break; }
  }
  float* out = (float*)d_out;
  if (chunkT == 0) {
    diag_kernel<<<1, 1, 0, stream>>>(out, 12345.0f);
    return;
  }
  f32x4* Xg = (f32x4*)alloc((size_t)chunkT * 2 * 64 * 768 * 4 + XPAD);
  float* dout_h = out + (size_t)TB * 512;

  auto packw = [&](const float* W, int rows, int kb, int ntl, int ktl, int mode, unsigned short* dst) {
    int total = ntl * ktl * 64;
    pack_w_kernel<<<(total + 255) / 256, 256, 0, stream>>>(W, rows, kb, ntl, ktl, mode, dst);
  };
  packw(fw_W0, 512, 0,   48, 8,  0, Wx0p);
  packw(bw_W0, 512, 0,   48, 8,  0, Wx0p + 48 * 8 * 64 * 8);
  packw(fw_W1, 768, 0,   48, 16, 0, Wx1p);
  packw(bw_W1, 768, 0,   48, 16, 0, Wx1p + 48 * 16 * 64 * 8);
  packw(fw_W0, 512, 256, 32, 8,  1, Whrz0);
  packw(bw_W0, 512, 256, 32, 8,  1, Whrz0 + 32 * 8 * 64 * 8);
  packw(fw_W0, 512, 256, 16, 8,  2, Whc0);
  packw(bw_W0, 512, 256, 16, 8,  2, Whc0 + 16 * 8 * 64 * 8);
  packw(fw_W1, 768, 512, 32, 8,  1, Whrz1);
  packw(bw_W1, 768, 512, 32, 8,  1, Whrz1 + 32 * 8 * 64 * 8);
  packw(fw_W1, 768, 512, 16, 8,  2, Whc1);
  packw(bw_W1, 768, 512, 16, 8,  2, Whc1 + 16 * 8 * 64 * 8);

  dim3 rgrid(4, 2);
  // layer 0
  for (int t0 = 0; t0 < T_STEPS; t0 += chunkT) {
    dim3 ggrid(chunkT / 2, 6, 2);
    gemm_xg_kernel<0><<<ggrid, 256, 0, stream>>>(x, nullptr, nullptr, Wx0p, fw_b0, bw_b0, Xg, t0, chunkT);
    gru_kernel<0><<<rgrid, 512, 0, stream>>>(Xg,
        (const uint4*)Whrz0, (const uint4*)(Whrz0 + 32 * 8 * 64 * 8),
        (const uint4*)Whc0,  (const uint4*)(Whc0 + 16 * 8 * 64 * 8),
        fs0, bs0, nullptr, hstate, dout_h, t0, chunkT);
  }
  // layer 1
  for (int t0 = 0; t0 < T_STEPS; t0 += chunkT) {
    dim3 ggrid(chunkT / 2, 6, 2);
    gemm_xg_kernel<1><<<ggrid, 256, 0, stream>>>(nullptr, fs0, bs0, Wx1p, fw_b1, bw_b1, Xg, t0, chunkT);
    gru_kernel<1><<<rgrid, 512, 0, stream>>>(Xg,
        (const uint4*)Whrz1, (const uint4*)(Whrz1 + 32 * 8 * 64 * 8),
        (const uint4*)Whc1,  (const uint4*)(Whc1 + 16 * 8 * 64 * 8),
        nullptr, nullptr, out, hstate, dout_h, t0, chunkT);
  }
}

// Round 15
// 2184.681 us; speedup vs baseline: 1.2107x; 1.0101x over previous
//
#include <hip/hip_runtime.h>
#include <hip/hip_bf16.h>

#define T_STEPS 512
#define BATCH 64
#define TB (T_STEPS * BATCH)   // 32768

typedef short bf16x8 __attribute__((ext_vector_type(8)));
typedef float f32x4 __attribute__((ext_vector_type(4)));

union FragU { uint4 u; bf16x8 v; };

static __device__ __forceinline__ bf16x8 ld_frag(const uint4* p) {
  FragU f; f.u = *p; return f.v;
}

static __device__ __forceinline__ unsigned short f2bf(float f) {
  unsigned u = __float_as_uint(f);
  return (unsigned short)((u + 0x7FFFu + ((u >> 16) & 1u)) >> 16);
}

// packed f32->bf16 (RNE), 1 inst per pair
static __device__ __forceinline__ unsigned cvt_pk_bf16(float lo, float hi) {
  unsigned r;
  asm("v_cvt_pk_bf16_f32 %0, %1, %2" : "=v"(r) : "v"(lo), "v"(hi));
  return r;
}

static __device__ __forceinline__ int revrow(int r) {
  int t = r >> 6, b = r & 63;
  return ((T_STEPS - 1 - t) << 6) | b;
}

#define S_RZ  (-1.4426950408889634f)
#define S_C   (-2.8853900817779268f)

// ---- explicit named-AGPR weight residency (round-8..14-validated) --------------------
#define AWR(N, x) asm volatile("v_accvgpr_write_b32 a" #N ", %0" :: "v"(x) : "a" #N)
#define LOADF(F, A0, A1, A2, A3) do { \
    const int c_ = (F) >> 3, kt_ = (F) & 7; \
    const int nt_ = (c_ < 2) ? (w * 2 + c_) : (14 + w * 2 + c_); \
    uint4 t = whrzp[((size_t)nt_ * 8 + kt_) * 64 + lane]; \
    AWR(A0, t.x); AWR(A1, t.y); AWR(A2, t.z); AWR(A3, t.w); } while (0)

#define MFMA_A(acc, va, B0, B3) \
  asm volatile("v_mfma_f32_16x16x32_bf16 %0, %1, a[" #B0 ":" #B3 "], %0" \
               : "+v"(acc) : "v"(va))
#define MFMA_AZ(acc, va, B0, B3, zq) \
  asm volatile("v_mfma_f32_16x16x32_bf16 %0, %1, a[" #B0 ":" #B3 "], %2" \
               : "=&v"(acc) : "v"(va), "v"(zq))
#define MFMA_V(acc, va, vb) \
  asm volatile("v_mfma_f32_16x16x32_bf16 %0, %1, %2, %0" \
               : "+v"(acc) : "v"(va), "v"(vb))
#define MFMA_VZ(acc, va, vb, zq) \
  asm volatile("v_mfma_f32_16x16x32_bf16 %0, %1, %2, %3" \
               : "=&v"(acc) : "v"(va), "v"(vb), "v"(zq))
#define ACCFENCE2(a, b) asm volatile("s_nop 7\n\ts_nop 7" : "+v"(a), "+v"(b))

#define ACLB \
  "a0","a1","a2","a3","a4","a5","a6","a7","a8","a9","a10","a11","a12","a13","a14","a15", \
  "a16","a17","a18","a19","a20","a21","a22","a23","a24","a25","a26","a27","a28","a29","a30","a31", \
  "a32","a33","a34","a35","a36","a37","a38","a39","a40","a41","a42","a43","a44","a45","a46","a47", \
  "a48","a49","a50","a51","a52","a53","a54","a55","a56","a57","a58","a59","a60","a61","a62","a63", \
  "a64","a65","a66","a67","a68","a69","a70","a71","a72","a73","a74","a75","a76","a77","a78","a79", \
  "a80","a81","a82","a83","a84","a85","a86","a87","a88","a89","a90","a91","a92","a93","a94","a95", \
  "a96","a97","a98","a99","a100","a101","a102","a103","a104","a105","a106","a107","a108","a109","a110","a111", \
  "a112","a113","a114","a115","a116","a117","a118","a119","a120","a121","a122","a123","a124","a125","a126","a127"

// ---------------- merged weight-pack kernel (12 jobs in one launch) -------------------
// modes: 0 = X3 (768 cols, [r|cand|z], g=n>>8), 1 = RZ (512 cols), 2 = C (256 cols)
static __device__ __forceinline__ void pack_one(const float* W, int rows, int k_base,
                                                int n_tiles, int k_tiles, int mode,
                                                unsigned short* dst, int gid) {
  int total = n_tiles * k_tiles * 64;
  if (gid >= total) return;
  int lane = gid & 63;
  int fi = gid >> 6;
  int kt = fi % k_tiles;
  int nt = fi / k_tiles;
  int n = nt * 16 + (lane & 15);
  int g, col; float s;
  if (mode == 0)      { g = n >> 8;            col = n & 255; s = (g == 1) ? S_C : S_RZ; }
  else if (mode == 1) { g = (n < 256) ? 0 : 2; col = n & 255; s = S_RZ; }
  else                { g = 1;                 col = n;       s = S_C; }
  int k0 = k_base + kt * 32 + ((lane >> 4) << 3);
  const float* src = W + ((size_t)g * rows + k0) * 256 + col;
  unsigned short v[8];
#pragma unroll
  for (int j = 0; j < 8; ++j) v[j] = f2bf(src[(size_t)j * 256] * s);
  uint4 o;
  o.x = v[0] | ((unsigned)v[1] << 16);
  o.y = v[2] | ((unsigned)v[3] << 16);
  o.z = v[4] | ((unsigned)v[5] << 16);
  o.w = v[6] | ((unsigned)v[7] << 16);
  ((uint4*)dst)[gid] = o;
}

__global__ void pack_all_kernel(const float* __restrict__ fw_W0, const float* __restrict__ bw_W0,
                                const float* __restrict__ fw_W1, const float* __restrict__ bw_W1,
                                unsigned short* __restrict__ Wx0p, unsigned short* __restrict__ Wx1p,
                                unsigned short* __restrict__ Whrz0, unsigned short* __restrict__ Whc0,
                                unsigned short* __restrict__ Whrz1, unsigned short* __restrict__ Whc1) {
  int gid = blockIdx.x * blockDim.x + threadIdx.x;
  switch (blockIdx.y) {
    case 0:  pack_one(fw_W0, 512, 0,   48, 8,  0, Wx0p, gid); break;
    case 1:  pack_one(bw_W0, 512, 0,   48, 8,  0, Wx0p + 48 * 8 * 512, gid); break;
    case 2:  pack_one(fw_W1, 768, 0,   48, 16, 0, Wx1p, gid); break;
    case 3:  pack_one(bw_W1, 768, 0,   48, 16, 0, Wx1p + 48 * 16 * 512, gid); break;
    case 4:  pack_one(fw_W0, 512, 256, 32, 8,  1, Whrz0, gid); break;
    case 5:  pack_one(bw_W0, 512, 256, 32, 8,  1, Whrz0 + 32 * 8 * 512, gid); break;
    case 6:  pack_one(fw_W0, 512, 256, 16, 8,  2, Whc0, gid); break;
    case 7:  pack_one(bw_W0, 512, 256, 16, 8,  2, Whc0 + 16 * 8 * 512, gid); break;
    case 8:  pack_one(fw_W1, 768, 512, 32, 8,  1, Whrz1, gid); break;
    case 9:  pack_one(bw_W1, 768, 512, 32, 8,  1, Whrz1 + 32 * 8 * 512, gid); break;
    case 10: pack_one(fw_W1, 768, 512, 16, 8,  2, Whc1, gid); break;
    default: pack_one(bw_W1, 768, 512, 16, 8,  2, Whc1 + 16 * 8 * 512, gid); break;
  }
}

static __device__ __forceinline__ bf16x8 cvt8(float4 f0, float4 f1) {
  uint4 o;
  o.x = f2bf(f0.x) | ((unsigned)f2bf(f0.y) << 16);
  o.y = f2bf(f0.z) | ((unsigned)f2bf(f0.w) << 16);
  o.z = f2bf(f1.x) | ((unsigned)f2bf(f1.y) << 16);
  o.w = f2bf(f1.z) | ((unsigned)f2bf(f1.w) << 16);
  FragU f; f.u = o; return f.v;
}

// ---------------- Xg GEMM (chunked): writes C-fragment tile layout --------------------
template<int LAYER>
__global__ __launch_bounds__(256)
void gemm_xg_kernel(const float* __restrict__ x,
                    const unsigned short* __restrict__ fs0,
                    const unsigned short* __restrict__ bs0,
                    const unsigned short* __restrict__ Bp,
                    const float* __restrict__ bias_fw,
                    const float* __restrict__ bias_bw,
                    f32x4* __restrict__ Xg, int t0, int chunkT)
{
  constexpr int KT = (LAYER == 0) ? 8 : 16;
  int dir = blockIdx.z;
  int lane = threadIdx.x & 63;
  int w = threadIdx.x >> 6;
  int ww = w >> 1, wc = w & 1;
  int mt0 = blockIdx.x * 8 + ww * 4;
  int nt0 = blockIdx.y * 8 + wc * 4;
  const uint4* B = (const uint4*)Bp + (size_t)dir * 48 * KT * 64;
  const int arow = lane & 15;
  const int k0b = ((lane >> 4) << 3);

  f32x4 acc[4][4] = {};
#pragma unroll
  for (int kt = 0; kt < KT; ++kt) {
    int k0 = kt * 32 + k0b;
    bf16x8 a[4], b[4];
#pragma unroll
    for (int i = 0; i < 4; ++i) {
      int grow = t0 * 64 + (mt0 + i) * 16 + arow;
      if (LAYER == 0) {
        int gr = dir ? revrow(grow) : grow;
        const float4* s = (const float4*)(x + (size_t)gr * 256 + k0);
        a[i] = cvt8(s[0], s[1]);
      } else {
        const unsigned short* base; int r2 = grow, kk = k0;
        if (k0 < 256) { base = dir ? bs0 : fs0; }
        else          { base = dir ? fs0 : bs0; r2 = revrow(grow); kk = k0 - 256; }
        a[i] = *(const bf16x8*)(base + (size_t)r2 * 256 + kk);
      }
    }
#pragma unroll
    for (int j = 0; j < 4; ++j) b[j] = ld_frag(B + ((size_t)(nt0 + j) * KT + kt) * 64 + lane);
#pragma unroll
    for (int i = 0; i < 4; ++i)
#pragma unroll
      for (int j = 0; j < 4; ++j)
        acc[i][j] = __builtin_amdgcn_mfma_f32_16x16x32_bf16(a[i], b[j], acc[i][j], 0, 0, 0);
  }

  const float* bias = dir ? bias_bw : bias_fw;
  f32x4* C = Xg + (size_t)dir * (chunkT * 4) * 48 * 64;
#pragma unroll
  for (int j = 0; j < 4; ++j) {
    int ct = nt0 + j;
    int col = ct * 16 + (lane & 15);
    int g = col >> 8, cc = col & 255;
    float bv = ((g == 1) ? S_C : S_RZ) * bias[g * 256 + cc];
#pragma unroll
    for (int i = 0; i < 4; ++i) {
      int rt = blockIdx.x * 8 + ww * 4 + i;
      f32x4 v = acc[i][j];
      v[0] += bv; v[1] += bv; v[2] += bv; v[3] += bv;
      C[((size_t)rt * 48 + ct) * 64 + lane] = v;
    }
  }
}

// ---------------- persistent recurrent GRU kernel (round-14-validated) ----------------
// grid (4, 2), 512 threads = 8 waves. Whrz in physical a0..a127; Whc in LDS.
// Phase-balanced: phase A = r only; phase B = z (register-only) overlapping rh+wc reads.
template<int LAYER>
__global__ __launch_bounds__(512) __attribute__((amdgpu_waves_per_eu(2, 2)))
void gru_kernel(const f32x4* __restrict__ Xg,
                const uint4* __restrict__ whrz_fw, const uint4* __restrict__ whrz_bw, // [32][8][64]
                const uint4* __restrict__ whc_fw,  const uint4* __restrict__ whc_bw,  // [16][8][64]
                unsigned short* __restrict__ sfw_bf, unsigned short* __restrict__ sbw_bf,
                float* __restrict__ out,
                float* __restrict__ hstate, float* __restrict__ dout_h,
                int t0, int chunkT)
{
  const int dir = blockIdx.y;
  const int bx = blockIdx.x;
  const int row0 = bx * 16;
  const int tid = threadIdx.x;
  const int lane = tid & 63;
  const int w = tid >> 6;               // 0..7

  __shared__ __align__(16) unsigned short hx[2 * 16 * 256];
  __shared__ __align__(16) uint4 wc_lds[16 * 8 * 64];       // Whc B-fragments (128 KB)

  const uint4* whrzp = dir ? whrz_bw : whrz_fw;
  const uint4* whcp  = dir ? whc_bw  : whc_fw;

  for (int i = tid; i < 16 * 8 * 64; i += 512) wc_lds[i] = whcp[i];

  LOADF(0, 0, 1, 2, 3);     LOADF(1, 4, 5, 6, 7);     LOADF(2, 8, 9, 10, 11);   LOADF(3, 12, 13, 14, 15);
  LOADF(4, 16, 17, 18, 19); LOADF(5, 20, 21, 22, 23); LOADF(6, 24, 25, 26, 27); LOADF(7, 28, 29, 30, 31);
  LOADF(8, 32, 33, 34, 35); LOADF(9, 36, 37, 38, 39); LOADF(10, 40, 41, 42, 43); LOADF(11, 44, 45, 46, 47);
  LOADF(12, 48, 49, 50, 51); LOADF(13, 52, 53, 54, 55); LOADF(14, 56, 57, 58, 59); LOADF(15, 60, 61, 62, 63);
  LOADF(16, 64, 65, 66, 67); LOADF(17, 68, 69, 70, 71); LOADF(18, 72, 73, 74, 75); LOADF(19, 76, 77, 78, 79);
  LOADF(20, 80, 81, 82, 83); LOADF(21, 84, 85, 86, 87); LOADF(22, 88, 89, 90, 91); LOADF(23, 92, 93, 94, 95);
  LOADF(24, 96, 97, 98, 99); LOADF(25, 100, 101, 102, 103); LOADF(26, 104, 105, 106, 107); LOADF(27, 108, 109, 110, 111);
  LOADF(28, 112, 113, 114, 115); LOADF(29, 116, 117, 118, 119); LOADF(30, 120, 121, 122, 123); LOADF(31, 124, 125, 126, 127);

  const int ccol = lane & 15;
  const int crow = ((lane >> 4) << 2);     // 0,4,8,12

#define SWZ(rr, cb) ((rr) * 512 + ((((cb) & ~15) ^ (((rr) & 7) << 4) ^ (((rr) & 8) << 2)) | ((cb) & 15)))

  float* hst = hstate + (size_t)(dir * 4 + bx) * 4096;
  for (int i = tid; i < 16 * 256; i += 512) {
    float v = (t0 == 0) ? 0.0f : hst[i];
    int rr = i >> 8, cc = i & 255;
    *(unsigned short*)((char*)hx + 8192 + SWZ(rr, cc * 2)) = f2bf(v);
  }
  float hreg[2][4];
#pragma unroll
  for (int j = 0; j < 2; ++j)
#pragma unroll
    for (int r = 0; r < 4; ++r) {
      int rr = crow + r, c = (w * 2 + j) * 16 + ccol;
      hreg[j][r] = (t0 == 0) ? 0.0f : hst[rr * 256 + c];
    }
  __syncthreads();

  const f32x4* XgD = Xg + (size_t)dir * (chunkT * 4) * 48 * 64;
  unsigned short* sp_bf = dir ? sbw_bf : sfw_bf;
  const int coff = dir ? 256 : 0;
  const int ardbase = (lane & 15) * 512;
  const int arxor = ((lane & 7) << 4) ^ ((lane & 8) << 2);
  const int afc = ((lane >> 4) << 4);

  const int ra0 = ardbase + ((0 * 64 + afc) ^ arxor);
  const int ra1 = ardbase + ((1 * 64 + afc) ^ arxor);
  const int ra2 = ardbase + ((2 * 64 + afc) ^ arxor);
  const int ra3 = ardbase + ((3 * 64 + afc) ^ arxor);
  const int ra4 = ardbase + ((4 * 64 + afc) ^ arxor);
  const int ra5 = ardbase + ((5 * 64 + afc) ^ arxor);
  const int ra6 = ardbase + ((6 * 64 + afc) ^ arxor);
  const int ra7 = ardbase + ((7 * 64 + afc) ^ arxor);
#define HF(RA)  (*(const bf16x8*)((const char*)hx + 8192 + (RA)))
#define RHF(RA) (*(const bf16x8*)((const char*)hx + (RA)))

  const int cbj0 = ((w * 2 + 0) * 16 + ccol) * 2;
  const int cbj1 = ((w * 2 + 1) * 16 + ccol) * 2;
  const int wa00 = SWZ(crow + 0, cbj0), wa01 = SWZ(crow + 1, cbj0);
  const int wa02 = SWZ(crow + 2, cbj0), wa03 = SWZ(crow + 3, cbj0);
  const int wa10 = SWZ(crow + 0, cbj1), wa11 = SWZ(crow + 1, cbj1);
  const int wa12 = SWZ(crow + 2, cbj1), wa13 = SWZ(crow + 3, cbj1);

  const size_t XSTEP = (size_t)4 * 48 * 64;
  const f32x4* pR = XgD + (size_t)bx * 48 * 64 + (size_t)(w * 2) * 64 + lane;
  const f32x4* pZ = pR + (size_t)32 * 64;
  const f32x4* pB = pR + (size_t)16 * 64;

  unsigned short* pSp = sp_bf + ((size_t)(t0 * 64 + row0 + crow) * 256) + (w * 2) * 16 + ccol;
  const int g0 = (LAYER == 1 && dir) ? ((T_STEPS - 1 - t0) * 64 + row0) : (t0 * 64 + row0);
  float* pO = out ? out + ((size_t)(g0 + crow) * 512) + coff + (w * 2) * 16 + ccol : nullptr;
  float* pO2 = pO ? pO + 2 * 512 : nullptr;
  const long long OSTEP = (LAYER == 1 && dir) ? -(long long)64 * 512 : (long long)64 * 512;

  f32x4 zq = {0.0f, 0.0f, 0.0f, 0.0f};

  // prologue: prefetch only the r-part Xg for step 0
  f32x4 xa0 = pR[0], xa1 = pR[64];

#pragma unroll 1
  for (int t = t0; t < t0 + chunkT; ++t) {
    // ---------- phase A: r = h @ Whr (16 MFMAs; h-frags kept in registers) ----------
    bf16x8 hf0 = HF(ra0), hf1 = HF(ra1), hf2 = HF(ra2), hf3 = HF(ra3);
    bf16x8 hf4 = HF(ra4), hf5 = HF(ra5), hf6 = HF(ra6), hf7 = HF(ra7);
    f32x4 accA0, accA1;
    MFMA_AZ(accA0, hf0, 0, 3, zq);   MFMA_AZ(accA1, hf0, 32, 35, zq);
    MFMA_A(accA0, hf1, 4, 7);    MFMA_A(accA1, hf1, 36, 39);
    MFMA_A(accA0, hf2, 8, 11);   MFMA_A(accA1, hf2, 40, 43);
    MFMA_A(accA0, hf3, 12, 15);  MFMA_A(accA1, hf3, 44, 47);
    MFMA_A(accA0, hf4, 16, 19);  MFMA_A(accA1, hf4, 48, 51);
    MFMA_A(accA0, hf5, 20, 23);  MFMA_A(accA1, hf5, 52, 55);
    MFMA_A(accA0, hf6, 24, 27);  MFMA_A(accA1, hf6, 56, 59);
    MFMA_A(accA0, hf7, 28, 31);  MFMA_A(accA1, hf7, 60, 63);
    ACCFENCE2(accA0, accA1);

    // epilogue A (r-gates): rh -> LDS via packed bf16 pairs
    {
      float rh0[4], rh1[4];
#pragma unroll
      for (int r = 0; r < 4; ++r) {
        float v0 = accA0[r] + xa0[r];
        rh0[r] = __builtin_amdgcn_rcpf(1.0f + __builtin_amdgcn_exp2f(v0)) * hreg[0][r];
        float v1 = accA1[r] + xa1[r];
        rh1[r] = __builtin_amdgcn_rcpf(1.0f + __builtin_amdgcn_exp2f(v1)) * hreg[1][r];
      }
      unsigned a01 = cvt_pk_bf16(rh0[0], rh0[1]);
      unsigned a23 = cvt_pk_bf16(rh0[2], rh0[3]);
      unsigned b01 = cvt_pk_bf16(rh1[0], rh1[1]);
      unsigned b23 = cvt_pk_bf16(rh1[2], rh1[3]);
      *(unsigned short*)((char*)hx + wa00) = (unsigned short)a01;
      *(unsigned short*)((char*)hx + wa01) = (unsigned short)(a01 >> 16);
      *(unsigned short*)((char*)hx + wa02) = (unsigned short)a23;
      *(unsigned short*)((char*)hx + wa03) = (unsigned short)(a23 >> 16);
      *(unsigned short*)((char*)hx + wa10) = (unsigned short)b01;
      *(unsigned short*)((char*)hx + wa11) = (unsigned short)(b01 >> 16);
      *(unsigned short*)((char*)hx + wa12) = (unsigned short)b23;
      *(unsigned short*)((char*)hx + wa13) = (unsigned short)(b23 >> 16);
    }
    asm volatile("s_waitcnt lgkmcnt(0)" ::: "memory", ACLB);
    __builtin_amdgcn_s_barrier();

    // ---------- phase B ----------
    f32x4 xz0 = pZ[0], xz1 = pZ[64], xb0 = pB[0], xb1 = pB[64];

    // z = h @ Whz — register-only MFMAs; rh + wc LDS reads issue in their shadow
    f32x4 accZ0, accZ1;
    MFMA_AZ(accZ0, hf0, 64, 67, zq);  MFMA_AZ(accZ1, hf0, 96, 99, zq);
    MFMA_A(accZ0, hf1, 68, 71);   MFMA_A(accZ1, hf1, 100, 103);
    MFMA_A(accZ0, hf2, 72, 75);   MFMA_A(accZ1, hf2, 104, 107);
    MFMA_A(accZ0, hf3, 76, 79);   MFMA_A(accZ1, hf3, 108, 111);
    MFMA_A(accZ0, hf4, 80, 83);   MFMA_A(accZ1, hf4, 112, 115);
    MFMA_A(accZ0, hf5, 84, 87);   MFMA_A(accZ1, hf5, 116, 119);
    MFMA_A(accZ0, hf6, 88, 91);   MFMA_A(accZ1, hf6, 120, 123);
    MFMA_A(accZ0, hf7, 92, 95);   MFMA_A(accZ1, hf7, 124, 127);

    hf0 = RHF(ra0); hf1 = RHF(ra1); hf2 = RHF(ra2); hf3 = RHF(ra3);
    hf4 = RHF(ra4); hf5 = RHF(ra5); hf6 = RHF(ra6); hf7 = RHF(ra7);

    ACCFENCE2(accZ0, accZ1);
    float zreg[2][4];
#pragma unroll
    for (int r = 0; r < 4; ++r) {
      zreg[0][r] = __builtin_amdgcn_rcpf(1.0f + __builtin_amdgcn_exp2f(accZ0[r] + xz0[r]));
      zreg[1][r] = __builtin_amdgcn_rcpf(1.0f + __builtin_amdgcn_exp2f(accZ1[r] + xz1[r]));
    }

    // cand = (r*h) @ Whc — wc streamed from LDS
    f32x4 accB0, accB1;
    MFMA_VZ(accB0, hf0, *(const bf16x8*)&wc_lds[((size_t)(w * 2 + 0) * 8 + 0) * 64 + lane], zq);
    MFMA_VZ(accB1, hf0, *(const bf16x8*)&wc_lds[((size_t)(w * 2 + 1) * 8 + 0) * 64 + lane], zq);
    MFMA_V(accB0, hf1, *(const bf16x8*)&wc_lds[((size_t)(w * 2 + 0) * 8 + 1) * 64 + lane]);
    MFMA_V(accB1, hf1, *(const bf16x8*)&wc_lds[((size_t)(w * 2 + 1) * 8 + 1) * 64 + lane]);
    MFMA_V(accB0, hf2, *(const bf16x8*)&wc_lds[((size_t)(w * 2 + 0) * 8 + 2) * 64 + lane]);
    MFMA_V(accB1, hf2, *(const bf16x8*)&wc_lds[((size_t)(w * 2 + 1) * 8 + 2) * 64 + lane]);
    MFMA_V(accB0, hf3, *(const bf16x8*)&wc_lds[((size_t)(w * 2 + 0) * 8 + 3) * 64 + lane]);
    MFMA_V(accB1, hf3, *(const bf16x8*)&wc_lds[((size_t)(w * 2 + 1) * 8 + 3) * 64 + lane]);
    MFMA_V(accB0, hf4, *(const bf16x8*)&wc_lds[((size_t)(w * 2 + 0) * 8 + 4) * 64 + lane]);
    MFMA_V(accB1, hf4, *(const bf16x8*)&wc_lds[((size_t)(w * 2 + 1) * 8 + 4) * 64 + lane]);
    MFMA_V(accB0, hf5, *(const bf16x8*)&wc_lds[((size_t)(w * 2 + 0) * 8 + 5) * 64 + lane]);
    MFMA_V(accB1, hf5, *(const bf16x8*)&wc_lds[((size_t)(w * 2 + 1) * 8 + 5) * 64 + lane]);
    MFMA_V(accB0, hf6, *(const bf16x8*)&wc_lds[((size_t)(w * 2 + 0) * 8 + 6) * 64 + lane]);
    MFMA_V(accB1, hf6, *(const bf16x8*)&wc_lds[((size_t)(w * 2 + 1) * 8 + 6) * 64 + lane]);
    MFMA_V(accB0, hf7, *(const bf16x8*)&wc_lds[((size_t)(w * 2 + 0) * 8 + 7) * 64 + lane]);
    MFMA_V(accB1, hf7, *(const bf16x8*)&wc_lds[((size_t)(w * 2 + 1) * 8 + 7) * 64 + lane]);
    ACCFENCE2(accB0, accB1);

#pragma unroll
    for (int j = 0; j < 2; ++j) {
      f32x4 ac = j ? accB1 : accB0;
      f32x4 xv = j ? xb1 : xb0;
      float hn[4];
#pragma unroll
      for (int r = 0; r < 4; ++r) {
        float v = ac[r] + xv[r];
        float cand = __builtin_amdgcn_rcpf(1.0f + __builtin_amdgcn_exp2f(v)) * 2.0f - 1.0f;
        hn[r] = cand + zreg[j][r] * (hreg[j][r] - cand);
        hreg[j][r] = hn[r];
      }
      unsigned p01 = cvt_pk_bf16(hn[0], hn[1]);
      unsigned p23 = cvt_pk_bf16(hn[2], hn[3]);
      int wA = j ? wa10 : wa00, wB = j ? wa11 : wa01;
      int wC = j ? wa12 : wa02, wD = j ? wa13 : wa03;
      *(unsigned short*)((char*)hx + 8192 + wA) = (unsigned short)p01;
      *(unsigned short*)((char*)hx + 8192 + wB) = (unsigned short)(p01 >> 16);
      *(unsigned short*)((char*)hx + 8192 + wC) = (unsigned short)p23;
      *(unsigned short*)((char*)hx + 8192 + wD) = (unsigned short)(p23 >> 16);
      if (LAYER == 0) {
        pSp[(size_t)j * 16 + 0 * 256] = (unsigned short)p01;
        pSp[(size_t)j * 16 + 1 * 256] = (unsigned short)(p01 >> 16);
        pSp[(size_t)j * 16 + 2 * 256] = (unsigned short)p23;
        pSp[(size_t)j * 16 + 3 * 256] = (unsigned short)(p23 >> 16);
      } else {
        pO[(size_t)j * 16 + 0 * 512] = hn[0];
        pO[(size_t)j * 16 + 1 * 512] = hn[1];
        pO2[(size_t)j * 16 + 0 * 512] = hn[2];
        pO2[(size_t)j * 16 + 1 * 512] = hn[3];
      }
    }
    if (LAYER == 0) pSp += (size_t)64 * 256;
    else { pO += OSTEP; pO2 += OSTEP; }

    // advance pointers; prefetch next step's r-part Xg (padded buffer)
    pR += XSTEP; pZ += XSTEP; pB += XSTEP;
    xa0 = pR[0]; xa1 = pR[64];

    asm volatile("s_waitcnt lgkmcnt(0)" ::: "memory", ACLB);
    __builtin_amdgcn_s_barrier();
  }

  // persist h; on last chunk also write fh/bh
#pragma unroll
  for (int j = 0; j < 2; ++j)
#pragma unroll
    for (int r = 0; r < 4; ++r) {
      int rr = crow + r, c = (w * 2 + j) * 16 + ccol;
      hst[rr * 256 + c] = hreg[j][r];
      if (t0 + chunkT == T_STEPS) {
        float* dst = dout_h + (dir ? 32768 : 0) + (size_t)LAYER * 16384;
        dst[(size_t)(row0 + rr) * 256 + c] = hreg[j][r];
      }
    }
}

__global__ void diag_kernel(float* out, float v) { out[0] = v; }

// --------------------------------------------------------------------------------------
extern "C" void kernel_launch(void* const* d_in, const int* in_sizes, int n_in,
                              void* d_out, int out_size, void* d_ws, size_t ws_size,
                              hipStream_t stream) {
  const float* x     = (const float*)d_in[0];
  const float* fw_W0 = (const float*)d_in[2];
  const float* fw_b0 = (const float*)d_in[3];
  const float* fw_W1 = (const float*)d_in[4];
  const float* fw_b1 = (const float*)d_in[5];
  const float* bw_W0 = (const float*)d_in[6];
  const float* bw_b0 = (const float*)d_in[7];
  const float* bw_W1 = (const float*)d_in[8];
  const float* bw_b1 = (const float*)d_in[9];

  char* ws = (char*)d_ws;
  size_t off = 0;
  auto alloc = [&](size_t bytes) -> char* {
    char* p = ws + off; off += (bytes + 255) & ~(size_t)255; return p;
  };
  unsigned short* Wx0p  = (unsigned short*)alloc(2ull * 48 * 8 * 64 * 8 * 2);
  unsigned short* Wx1p  = (unsigned short*)alloc(2ull * 48 * 16 * 64 * 8 * 2);
  unsigned short* Whrz0 = (unsigned short*)alloc(2ull * 32 * 8 * 64 * 8 * 2);
  unsigned short* Whc0  = (unsigned short*)alloc(2ull * 16 * 8 * 64 * 8 * 2);
  unsigned short* Whrz1 = (unsigned short*)alloc(2ull * 32 * 8 * 64 * 8 * 2);
  unsigned short* Whc1  = (unsigned short*)alloc(2ull * 16 * 8 * 64 * 8 * 2);
  unsigned short* fs0   = (unsigned short*)alloc((size_t)TB * 256 * 2);
  unsigned short* bs0   = (unsigned short*)alloc((size_t)TB * 256 * 2);
  float* hstate         = (float*)alloc(2ull * 4 * 16 * 256 * 4);

  const size_t XPAD = (size_t)4 * 48 * 64 * 16;
  int chunkT = 0;
  for (int ct = 512; ct >= 8; ct >>= 1) {
    if (off + (size_t)ct * 2 * 64 * 768 * 4 + XPAD <= ws_size) { chunkT = ct; break; }
  }
  float* out = (float*)d_out;
  if (chunkT == 0) {
    diag_kernel<<<1, 1, 0, stream>>>(out, 12345.0f);
    return;
  }
  f32x4* Xg = (f32x4*)alloc((size_t)chunkT * 2 * 64 * 768 * 4 + XPAD);
  float* dout_h = out + (size_t)TB * 512;

  // single merged pack launch (12 jobs; largest job needs 192 blocks of 256 threads)
  { dim3 pg(192, 12);
    pack_all_kernel<<<pg, 256, 0, stream>>>(fw_W0, bw_W0, fw_W1, bw_W1,
                                            Wx0p, Wx1p, Whrz0, Whc0, Whrz1, Whc1); }

  dim3 rgrid(4, 2);
  // layer 0
  for (int t0 = 0; t0 < T_STEPS; t0 += chunkT) {
    dim3 ggrid(chunkT / 2, 6, 2);
    gemm_xg_kernel<0><<<ggrid, 256, 0, stream>>>(x, nullptr, nullptr, Wx0p, fw_b0, bw_b0, Xg, t0, chunkT);
    gru_kernel<0><<<rgrid, 512, 0, stream>>>(Xg,
        (const uint4*)Whrz0, (const uint4*)(Whrz0 + 32 * 8 * 64 * 8),
        (const uint4*)Whc0,  (const uint4*)(Whc0 + 16 * 8 * 64 * 8),
        fs0, bs0, nullptr, hstate, dout_h, t0, chunkT);
  }
  // layer 1
  for (int t0 = 0; t0 < T_STEPS; t0 += chunkT) {
    dim3 ggrid(chunkT / 2, 6, 2);
    gemm_xg_kernel<1><<<ggrid, 256, 0, stream>>>(nullptr, fs0, bs0, Wx1p, fw_b1, bw_b1, Xg, t0, chunkT);
    gru_kernel<1><<<rgrid, 512, 0, stream>>>(Xg,
        (const uint4*)Whrz1, (const uint4*)(Whrz1 + 32 * 8 * 64 * 8),
        (const uint4*)Whc1,  (const uint4*)(Whc1 + 16 * 8 * 64 * 8),
        nullptr, nullptr, out, hstate, dout_h, t0, chunkT);
  }
}